// Round 11
// baseline (127.069 us; speedup 1.0000x reference)
//
#include <hip/hip_runtime.h>
#include <hip/hip_fp16.h>
#include <math.h>

#define PI_D 3.141592653589793

typedef _Float16 h2 __attribute__((ext_vector_type(2)));
typedef _Float16 h4 __attribute__((ext_vector_type(4)));
typedef _Float16 h8 __attribute__((ext_vector_type(8)));
typedef unsigned short us8 __attribute__((ext_vector_type(8)));
typedef __fp16 f16v2 __attribute__((ext_vector_type(2)));
typedef __fp16 f16v8 __attribute__((ext_vector_type(8)));
typedef float f32x4 __attribute__((ext_vector_type(4)));

#define STR1 264     // gl1h/gr1h row stride in halves (528 B, 16B-aligned; 33 h8)
#define STR2H 72     // gl2h/gr2h fp16 row stride in halves (144 B)

#define SV(v, a, b) __builtin_shufflevector(v, v, a, b)

static __device__ __forceinline__ h2 pack_h2(float a, float b) {
    return __builtin_bit_cast(h2, __builtin_amdgcn_cvt_pkrtz(a, b));
}

static __device__ __forceinline__ float fdot2(h2 a, h2 b, float c) {
    return __builtin_amdgcn_fdot2(__builtin_bit_cast(f16v2, a),
                                  __builtin_bit_cast(f16v2, b), c, false);
}

static __device__ __forceinline__ h8 habs8(h8 x) {
    us8 u = __builtin_bit_cast(us8, x);
    us8 m = {0x7fff, 0x7fff, 0x7fff, 0x7fff, 0x7fff, 0x7fff, 0x7fff, 0x7fff};
    return __builtin_bit_cast(h8, (us8)(u & m));
}

static __device__ __forceinline__ f32x4 mfma16(h8 a, h8 b, f32x4 c) {
    return __builtin_amdgcn_mfma_f32_16x16x32_f16(
        __builtin_bit_cast(f16v8, a), __builtin_bit_cast(f16v8, b), c, 0, 0, 0);
}

// ---- pre-pass: pack weights to fp16 ----
// ws h8 segments: [0..2048) Wl2 (MFMA B-frag), [2048..4096) Wr2 (MFMA B-frag),
//                 [4096..6144) fc1 [col][k] (256 x 8), [6144..14336) fc2 [col][k] (256 x 32)
__global__ __launch_bounds__(256) void pack_weights_kernel(
    const float* __restrict__ Wl2, const float* __restrict__ Wr2,
    const float* __restrict__ fc1_w, const float* __restrict__ fc2_w,
    h8* __restrict__ ws)
{
    int idx = blockIdx.x * 256 + threadIdx.x;
    if (idx < 4096) {
        const float* W = idx < 2048 ? Wl2 : Wr2;
        int t = idx & 2047;
        int ntile = t >> 9, rem = t & 511;
        int kchunk = rem >> 6, lane = rem & 63;
        int n = ntile * 16 + (lane & 15);
        int k0 = kchunk * 32 + (lane >> 4) * 8;
        h8 o;
        #pragma unroll
        for (int j = 0; j < 8; ++j) o[j] = (_Float16)W[(k0 + j) * 64 + n];
        ws[idx] = o;
    } else if (idx < 6144) {
        int t = idx - 4096;                 // 256 cols x 8 chunks
        int col = t >> 3, kk = t & 7;
        h8 o;
        #pragma unroll
        for (int j = 0; j < 8; ++j) o[j] = (_Float16)fc1_w[(kk * 8 + j) * 256 + col];
        ws[idx] = o;
    } else {
        int t = idx - 6144;                 // 256 cols x 32 chunks
        int col = t >> 5, kk = t & 31;
        h8 o;
        #pragma unroll
        for (int j = 0; j < 8; ++j) o[j] = (_Float16)fc2_w[(kk * 8 + j) * 256 + col];
        ws[idx] = o;
    }
}

__global__ __launch_bounds__(256, 4) void actor_fused_kernel(
    const float* __restrict__ state24,
    const float* __restrict__ Wl1, const float* __restrict__ Wr1,
    const float* __restrict__ att1, const float* __restrict__ b1,
    const float* __restrict__ att2, const float* __restrict__ b2,
    const float* __restrict__ fc1_b, const float* __restrict__ fc2_b,
    const float* __restrict__ fc3_w, const float* __restrict__ fc3_b,
    const h8* __restrict__ wsL, const h8* __restrict__ wsR,
    const h8* __restrict__ wsF1, const h8* __restrict__ wsF2,
    float* __restrict__ out, int B)
{
    const int bix = blockIdx.x;
    if (bix >= B) return;
    const int tid = threadIdx.x;

    __shared__ float sinL[20], cosL[20], laserL[20], robotL[4];
    __shared__ __align__(16) h2 attLh[128];      // 0.4*att1 fp16 pairs [h][32]
    __shared__ __align__(16) h2 att2Lh[32];      // 0.4*att2 fp16 pairs
    __shared__ __align__(16) _Float16 gr1h[21 * STR1];   // r-transform, then h1
    __shared__ __align__(16) union {
        struct { _Float16 gl1h[21 * STR1];            // 11088 B
                 float ePf[84 * 24];                   // 8064 B: logits -> fp16 A-frag rows
                 float uv[168]; } p1;
        struct { _Float16 gl2h[21 * STR2H];
                 _Float16 gr2h[21 * STR2H];
                 _Float16 gl2hT[64 * 32];             // [col][k]; k>=21 garbage (A-zeros cover)
                 float e2[32 * 24];                    // logits -> fp16 A-frag; rows 21..31 zero
                 float u2v2[42];
                 _Float16 nfvh[64]; _Float16 hah[256]; _Float16 hbh[256]; } p2;
    } U;

    // ---- setup ----
    if (tid < 20) {
        double step = (PI_D + 0.03) / 20.0;
        float bound = (float)(-PI_D / 2.0 - 0.03 + (double)tid * step);
        float ang = bound + (float)(PI_D / 20.0);
        sinL[tid] = sinf(ang);
        cosL[tid] = cosf(ang);
        laserL[tid] = state24[bix * 24 + tid] * 0.1f;
    }
    if (tid >= 32 && tid < 36) robotL[tid - 32] = state24[bix * 24 + 20 + (tid - 32)];
    if (tid < 128) {
        float2 ap = ((const float2*)att1)[tid];
        attLh[tid] = pack_h2(0.4f * ap.x, 0.4f * ap.y);
    }
    if (tid >= 128 && tid < 160) {
        float2 ap = ((const float2*)att2)[tid - 128];
        att2Lh[tid - 128] = pack_h2(0.4f * ap.x, 0.4f * ap.y);
    }
    __syncthreads();

    // ---- layer-1 transforms -> fp16 LDS ----
    {
        const int d2 = tid & 127;      // dims 2*d2, 2*d2+1
        const int half = tid >> 7;     // 0 -> nodes 0..10, 1 -> nodes 11..20
        float2 wl[7], wr[7];
        #pragma unroll
        for (int k = 0; k < 7; k++) {
            wl[k] = ((const float2*)Wl1)[k * 128 + d2];
            wr[k] = ((const float2*)Wr1)[k * 128 + d2];
        }
        const int base = half * 11;
        #pragma unroll
        for (int nn = 0; nn < 11; ++nn) {
            int node = base + nn;
            if (node < 21) {
                float a0, a1, b0, b1v;
                if (node < 20) {
                    float l = laserL[node], s = sinL[node], c = cosL[node];
                    a0 = l * wl[0].x + s * wl[1].x + c * wl[2].x;
                    a1 = l * wl[0].y + s * wl[1].y + c * wl[2].y;
                    b0 = l * wr[0].x + s * wr[1].x + c * wr[2].x;
                    b1v = l * wr[0].y + s * wr[1].y + c * wr[2].y;
                } else {
                    float r0 = robotL[0], r1 = robotL[1], r2 = robotL[2], r3 = robotL[3];
                    a0 = r0 * wl[3].x + r1 * wl[4].x + r2 * wl[5].x + r3 * wl[6].x;
                    a1 = r0 * wl[3].y + r1 * wl[4].y + r2 * wl[5].y + r3 * wl[6].y;
                    b0 = r0 * wr[3].x + r1 * wr[4].x + r2 * wr[5].x + r3 * wr[6].x;
                    b1v = r0 * wr[3].y + r1 * wr[4].y + r2 * wr[5].y + r3 * wr[6].y;
                }
                ((h2*)(U.p1.gl1h + node * STR1))[d2] = pack_h2(a0, a1);
                ((h2*)(gr1h + node * STR1))[d2] = pack_h2(b0, b1v);
            }
        }
    }
    __syncthreads();

    // ---- layer-1 logits (abs part) with register-cached gr row + fused u/v ----
    {
        const int h = tid >> 6;           // wave-uniform head
        const int lane = tid & 63;
        h2 ar[32];
        #pragma unroll
        for (int q = 0; q < 32; ++q) ar[q] = attLh[h * 32 + q];

        if (lane < 63) {
            const int i = lane / 3;                 // 0..20
            const int jg = lane - i * 3;            // 0..2 (7 j's each)
            const h8* gB8 = (const h8*)(gr1h + i * STR1 + h * 64);
            h8 br[8];
            #pragma unroll
            for (int ch = 0; ch < 8; ++ch) br[ch] = gB8[ch];
            const h8* gA8 = (const h8*)(U.p1.gl1h + (jg * 7) * STR1 + h * 64);
            float* eo = U.p1.ePf + (h * 21 + i) * 24 + jg * 7;
            #pragma unroll
            for (int s = 0; s < 7; ++s) {
                float m0 = 0.f, m1 = 0.f;
                #pragma unroll
                for (int ch = 0; ch < 8; ++ch) {
                    h8 x = gA8[ch] + br[ch];
                    h8 ax = habs8(x);
                    m0 = fdot2(SV(ax, 0, 1), ar[ch * 4 + 0], m0);
                    m1 = fdot2(SV(ax, 2, 3), ar[ch * 4 + 1], m1);
                    m0 = fdot2(SV(ax, 4, 5), ar[ch * 4 + 2], m0);
                    m1 = fdot2(SV(ax, 6, 7), ar[ch * 4 + 3], m1);
                }
                eo[s] = m0 + m1;
                gA8 += 33;                // next j row
            }
        }
        // fused u/v: uv[t<84] = 0.4att_h.gl1[j], uv[84+..] = 0.4att_h.gr1[i]
        if (tid < 168) {
            int r = tid < 84 ? tid : tid - 84;
            int hu = r / 21, idx = r - hu * 21;
            const _Float16* rowp = (tid < 84 ? U.p1.gl1h : gr1h) + idx * STR1 + hu * 64;
            const h8* row8 = (const h8*)rowp;
            const h2* aru = attLh + hu * 32;
            float l0 = 0.f, l1 = 0.f;
            #pragma unroll
            for (int ch = 0; ch < 8; ++ch) {
                h8 g = row8[ch];
                l0 = fdot2(SV(g, 0, 1), aru[ch * 4 + 0], l0);
                l1 = fdot2(SV(g, 2, 3), aru[ch * 4 + 1], l1);
                l0 = fdot2(SV(g, 4, 5), aru[ch * 4 + 2], l0);
                l1 = fdot2(SV(g, 6, 7), aru[ch * 4 + 3], l1);
            }
            U.p1.uv[tid] = l0 + l1;
        }
    }
    __syncthreads();

    // ---- softmax-1: add linear, exp, normalize -> fp16 A-frag in place ----
    if (tid < 84) {
        int h = tid / 21, i = tid - h * 21;
        float* row = U.p1.ePf + tid * 24;
        const float* uu = U.p1.uv + h * 21;
        float vi = 1.5f * U.p1.uv[84 + h * 21 + i];
        float ebuf[21];
        float m = -1e30f;
        #pragma unroll
        for (int j = 0; j < 21; j++) {
            float e = row[j] + 1.5f * uu[j] + vi;
            ebuf[j] = e;
            m = fmaxf(m, e);
        }
        float s = 0.f;
        #pragma unroll
        for (int j = 0; j < 21; j++) { float v = __expf(ebuf[j] - m); ebuf[j] = v; s += v; }
        float rinv = 1.f / s;
        h8* hp8 = (h8*)(U.p1.ePf) + tid * 6;
        h8 o0, o1, o2;
        #pragma unroll
        for (int q = 0; q < 8; ++q) o0[q] = (_Float16)(ebuf[q] * rinv);
        #pragma unroll
        for (int q = 0; q < 8; ++q) o1[q] = (_Float16)(ebuf[8 + q] * rinv);
        #pragma unroll
        for (int q = 0; q < 5; ++q) o2[q] = (_Float16)(ebuf[16 + q] * rinv);
        o2[5] = (_Float16)0.f; o2[6] = (_Float16)0.f; o2[7] = (_Float16)0.f;
        h8 zz = {};
        hp8[0] = o0; hp8[1] = o1; hp8[2] = o2;
        hp8[3] = zz; hp8[4] = zz; hp8[5] = zz;   // k = 24..47 zero
    }
    __syncthreads();

    // ---- agg1 via MFMA (h1 = P_h @ gl1_h, +bias, ELU -> gr1h) + weight prefetch ----
    h8 pbL[8], pbR[8];
    {
        const int lane = tid & 63;
        const int w = tid >> 6;
        // prefetch transform2 B-frags (consumed next-next phase; latency hidden here)
        const h8* bLp = wsL + w * 512 + lane;
        const h8* bRp = wsR + w * 512 + lane;
        #pragma unroll
        for (int kc = 0; kc < 8; ++kc) { pbL[kc] = bLp[kc * 64]; pbR[kc] = bRp[kc * 64]; }

        const int h = w;
        const int mcol = lane & 15;
        const int quad = lane >> 4;
        const h8* Af = (const h8*)U.p1.ePf;
        h8 A0 = Af[(h * 21 + mcol) * 6 + quad];
        int m1r = 16 + mcol; if (m1r > 20) m1r = 20;          // rows>20: garbage, discarded
        h8 A1 = Af[(h * 21 + m1r) * 6 + quad];
        int rowoff[8];
        #pragma unroll
        for (int jj = 0; jj < 8; ++jj) {
            int rr = quad * 8 + jj;
            rowoff[jj] = (rr > 20 ? 20 : rr) * STR1;          // k>=21: A zeros cover
        }
        const int colbase = h * 64 + mcol;
        f32x4 z4 = {0.f, 0.f, 0.f, 0.f};
        #pragma unroll
        for (int t = 0; t < 4; ++t) {
            int col = colbase + t * 16;
            h8 bv;
            #pragma unroll
            for (int jj = 0; jj < 8; ++jj) bv[jj] = U.p1.gl1h[rowoff[jj] + col];
            f32x4 d0 = mfma16(A0, bv, z4);
            f32x4 d1 = mfma16(A1, bv, z4);
            float bb = b1[col];
            #pragma unroll
            for (int r = 0; r < 4; ++r) {
                int n0 = quad * 4 + r;
                float v = d0[r] + bb;
                v = v > 0.f ? v : __expf(v) - 1.f;
                gr1h[n0 * STR1 + col] = (_Float16)v;
                int n1 = 16 + quad * 4 + r;
                if (n1 < 21) {
                    float w2 = d1[r] + bb;
                    w2 = w2 > 0.f ? w2 : __expf(w2) - 1.f;
                    gr1h[n1 * STR1 + col] = (_Float16)w2;
                }
            }
        }
    }
    __syncthreads();

    // ---- layer-2 transforms via MFMA (weights already in registers) ----
    {
        const int lane = tid & 63;
        const int w = tid >> 6;
        const int mrow = lane & 15;
        const int quad = lane >> 4;
        int rowA1 = 16 + mrow; if (rowA1 > 20) rowA1 = 20;    // garbage rows discarded
        const h8* hA0 = (const h8*)(gr1h + mrow * STR1 + quad * 8);
        const h8* hA1 = (const h8*)(gr1h + rowA1 * STR1 + quad * 8);
        f32x4 aL0 = {0.f, 0.f, 0.f, 0.f}, aL1 = {0.f, 0.f, 0.f, 0.f};
        f32x4 aR0 = {0.f, 0.f, 0.f, 0.f}, aR1 = {0.f, 0.f, 0.f, 0.f};
        #pragma unroll
        for (int kc = 0; kc < 8; ++kc) {
            h8 A0 = hA0[kc * 4];
            h8 A1 = hA1[kc * 4];
            aL0 = mfma16(A0, pbL[kc], aL0);
            aL1 = mfma16(A1, pbL[kc], aL1);
            aR0 = mfma16(A0, pbR[kc], aR0);
            aR1 = mfma16(A1, pbR[kc], aR1);
        }
        const int col = w * 16 + mrow;
        #pragma unroll
        for (int r = 0; r < 4; ++r) {
            int row0 = quad * 4 + r;
            U.p2.gl2h[row0 * STR2H + col] = (_Float16)aL0[r];
            U.p2.gr2h[row0 * STR2H + col] = (_Float16)aR0[r];
            int row1 = 16 + row0;
            if (row1 < 21) {
                U.p2.gl2h[row1 * STR2H + col] = (_Float16)aL1[r];
                U.p2.gr2h[row1 * STR2H + col] = (_Float16)aR1[r];
            }
        }
        // transposed L: gl2hT[col][k]; k>=21 entries garbage (A-zeros cover in agg2)
        {
            h2 lo0 = pack_h2(aL0[0], aL0[1]);
            h2 hi0 = pack_h2(aL0[2], aL0[3]);
            h4 p0 = __builtin_shufflevector(lo0, hi0, 0, 1, 2, 3);
            *(h4*)(U.p2.gl2hT + col * 32 + quad * 4) = p0;
            h2 lo1 = pack_h2(aL1[0], aL1[1]);
            h2 hi1 = pack_h2(aL1[2], aL1[3]);
            h4 p1 = __builtin_shufflevector(lo1, hi1, 0, 1, 2, 3);
            *(h4*)(U.p2.gl2hT + col * 32 + 16 + quad * 4) = p1;
        }
    }
    __syncthreads();

    // ---- layer-2 logits (abs part, fp16) + u2/v2 in spare slots ----
    {
        h2 ar2[32];
        #pragma unroll
        for (int q = 0; q < 32; ++q) ar2[q] = att2Lh[q];

        #pragma unroll
        for (int it = 0; it < 2; ++it) {
            int t = it * 256 + tid;
            if (t < 441) {
                int i = t / 21;
                int j = t - i * 21;
                const h8* gA8 = (const h8*)(U.p2.gl2h + j * STR2H);
                const h8* gB8 = (const h8*)(U.p2.gr2h + i * STR2H);
                float m0 = 0.f, m1 = 0.f;
                #pragma unroll
                for (int ch = 0; ch < 8; ++ch) {
                    h8 x = gA8[ch] + gB8[ch];
                    h8 ax = habs8(x);
                    m0 = fdot2(SV(ax, 0, 1), ar2[ch * 4 + 0], m0);
                    m1 = fdot2(SV(ax, 2, 3), ar2[ch * 4 + 1], m1);
                    m0 = fdot2(SV(ax, 4, 5), ar2[ch * 4 + 2], m0);
                    m1 = fdot2(SV(ax, 6, 7), ar2[ch * 4 + 3], m1);
                }
                U.p2.e2[i * 24 + j] = m0 + m1;
            } else if (t < 483) {
                int u = t - 441;                  // 0..41
                int r = u < 21 ? u : u - 21;
                const _Float16* rowp = (u < 21 ? U.p2.gl2h : U.p2.gr2h) + r * STR2H;
                const h8* row8 = (const h8*)rowp;
                float l0 = 0.f, l1 = 0.f;
                #pragma unroll
                for (int ch = 0; ch < 8; ++ch) {
                    h8 g = row8[ch];
                    l0 = fdot2(SV(g, 0, 1), ar2[ch * 4 + 0], l0);
                    l1 = fdot2(SV(g, 2, 3), ar2[ch * 4 + 1], l1);
                    l0 = fdot2(SV(g, 4, 5), ar2[ch * 4 + 2], l0);
                    l1 = fdot2(SV(g, 6, 7), ar2[ch * 4 + 3], l1);
                }
                U.p2.u2v2[u] = l0 + l1;
            }
        }
    }
    __syncthreads();

    // ---- softmax-2 -> fp16 A-frag in place; zero rows 21..31 (mean-pool needs them) ----
    if (tid < 21) {
        float* row = U.p2.e2 + tid * 24;
        const float* uu = U.p2.u2v2;
        float vi = 1.5f * U.p2.u2v2[21 + tid];
        float ebuf[21];
        float m = -1e30f;
        #pragma unroll
        for (int j = 0; j < 21; j++) {
            float e = row[j] + 1.5f * uu[j] + vi;
            ebuf[j] = e;
            m = fmaxf(m, e);
        }
        float s = 0.f;
        #pragma unroll
        for (int j = 0; j < 21; j++) { float v = __expf(ebuf[j] - m); ebuf[j] = v; s += v; }
        float rinv = 1.f / s;
        h8* hp8 = (h8*)(U.p2.e2) + tid * 6;
        h8 o0, o1, o2;
        #pragma unroll
        for (int q = 0; q < 8; ++q) o0[q] = (_Float16)(ebuf[q] * rinv);
        #pragma unroll
        for (int q = 0; q < 8; ++q) o1[q] = (_Float16)(ebuf[8 + q] * rinv);
        #pragma unroll
        for (int q = 0; q < 5; ++q) o2[q] = (_Float16)(ebuf[16 + q] * rinv);
        o2[5] = (_Float16)0.f; o2[6] = (_Float16)0.f; o2[7] = (_Float16)0.f;
        h8 zz = {};
        hp8[0] = o0; hp8[1] = o1; hp8[2] = o2;
        hp8[3] = zz; hp8[4] = zz; hp8[5] = zz;
    } else if (tid < 87) {
        int z = tid - 21;                 // rows 21..31 x 6 slots: true zeros (summed in pool)
        int rr = z / 6, slot = z - rr * 6;
        h8 zz = {};
        ((h8*)U.p2.e2)[(21 + rr) * 6 + slot] = zz;
    }
    __syncthreads();

    // ---- agg2 + mean-pool via MFMA -> nfvh direct ----
    {
        const int lane = tid & 63;
        const int w = tid >> 6;           // ntile
        const int mcol = lane & 15;
        const int quad = lane >> 4;
        const h8* Af2 = (const h8*)U.p2.e2;
        h8 A0 = Af2[mcol * 6 + quad];
        h8 A1 = Af2[(16 + mcol) * 6 + quad];   // rows 21..31 are true zeros
        h8 bv = *(const h8*)(U.p2.gl2hT + (w * 16 + mcol) * 32 + quad * 8);
        f32x4 z4 = {0.f, 0.f, 0.f, 0.f};
        f32x4 d0 = mfma16(A0, bv, z4);
        f32x4 d1 = mfma16(A1, bv, z4);
        float s = (d0[0] + d0[1]) + (d0[2] + d0[3])
                + (d1[0] + d1[1]) + (d1[2] + d1[3]);
        s += __shfl_xor(s, 16, 64);
        s += __shfl_xor(s, 32, 64);
        if (quad == 0) {
            int col = w * 16 + mcol;
            U.p2.nfvh[col] = (_Float16)(s * (1.f / 21.f) + b2[col]);
        }
    }
    __syncthreads();

    // ---- FC1 (64 -> 256): per-column packed weights, no k-split, no reduction ----
    {
        const h8* nf8 = (const h8*)U.p2.nfvh;
        h8 xv[8];
        #pragma unroll
        for (int q = 0; q < 8; ++q) xv[q] = nf8[q];     // broadcast reads
        const h8* wp = wsF1 + tid * 8;
        float a0 = 0.f, a1 = 0.f, a2 = 0.f, a3 = 0.f;
        #pragma unroll
        for (int kk = 0; kk < 8; ++kk) {
            h8 w = wp[kk];
            h8 xa = xv[kk];
            a0 = fdot2(SV(w, 0, 1), SV(xa, 0, 1), a0);
            a1 = fdot2(SV(w, 2, 3), SV(xa, 2, 3), a1);
            a2 = fdot2(SV(w, 4, 5), SV(xa, 4, 5), a2);
            a3 = fdot2(SV(w, 6, 7), SV(xa, 6, 7), a3);
        }
        float v = (a0 + a1) + (a2 + a3) + fc1_b[tid];
        U.p2.hah[tid] = (_Float16)fmaxf(v, 0.f);
    }
    __syncthreads();

    // ---- FC2 (256 -> 256): per-column packed weights, 4 accumulators ----
    {
        const h8* ha8 = (const h8*)U.p2.hah;
        const h8* wp = wsF2 + tid * 32;
        float a0 = 0.f, a1 = 0.f, a2 = 0.f, a3 = 0.f;
        #pragma unroll
        for (int q8 = 0; q8 < 32; ++q8) {
            h8 xa = ha8[q8];               // broadcast b128
            h8 w = wp[q8];
            a0 = fdot2(SV(w, 0, 1), SV(xa, 0, 1), a0);
            a1 = fdot2(SV(w, 2, 3), SV(xa, 2, 3), a1);
            a2 = fdot2(SV(w, 4, 5), SV(xa, 4, 5), a2);
            a3 = fdot2(SV(w, 6, 7), SV(xa, 6, 7), a3);
        }
        float v = (a0 + a1) + (a2 + a3) + fc2_b[tid];
        U.p2.hbh[tid] = (_Float16)fmaxf(v, 0.f);
    }
    __syncthreads();

    // ---- FC3 (256 -> 2) + tanh ----
    if (tid < 128) {
        int o = tid >> 6, l = tid & 63;
        float s = 0.f;
        #pragma unroll
        for (int m = 0; m < 4; m++) {
            int k = l + 64 * m;
            s = fmaf((float)U.p2.hbh[k], fc3_w[k * 2 + o], s);
        }
        #pragma unroll
        for (int off = 32; off >= 1; off >>= 1) s += __shfl_down(s, off, 64);
        if (l == 0) out[bix * 2 + o] = tanhf(s + fc3_b[o]);
    }
}

extern "C" void kernel_launch(void* const* d_in, const int* in_sizes, int n_in,
                              void* d_out, int out_size, void* d_ws, size_t ws_size,
                              hipStream_t stream) {
    const float* state24 = (const float*)d_in[0];
    const float* Wl1 = (const float*)d_in[1];
    const float* Wr1 = (const float*)d_in[2];
    const float* att1 = (const float*)d_in[3];
    const float* b1 = (const float*)d_in[4];
    const float* Wl2 = (const float*)d_in[5];
    const float* Wr2 = (const float*)d_in[6];
    const float* att2 = (const float*)d_in[7];
    const float* b2 = (const float*)d_in[8];
    const float* fc1_w = (const float*)d_in[9];
    const float* fc1_b = (const float*)d_in[10];
    const float* fc2_w = (const float*)d_in[11];
    const float* fc2_b = (const float*)d_in[12];
    const float* fc3_w = (const float*)d_in[13];
    const float* fc3_b = (const float*)d_in[14];
    float* out = (float*)d_out;

    h8* ws = (h8*)d_ws;                 // 14336 h8 = 224 KiB
    const h8* wsL = ws;
    const h8* wsR = ws + 2048;
    const h8* wsF1 = ws + 4096;
    const h8* wsF2 = ws + 6144;

    pack_weights_kernel<<<56, 256, 0, stream>>>(Wl2, Wr2, fc1_w, fc2_w, ws);

    int B = in_sizes[0] / 24;
    actor_fused_kernel<<<B, 256, 0, stream>>>(
        state24, Wl1, Wr1, att1, b1, att2, b2,
        fc1_b, fc2_b, fc3_w, fc3_b,
        wsL, wsR, wsF1, wsF2, out, B);
}

// Round 12
// 126.923 us; speedup vs baseline: 1.0012x; 1.0012x over previous
//
#include <hip/hip_runtime.h>
#include <hip/hip_fp16.h>
#include <math.h>

#define PI_D 3.141592653589793

typedef _Float16 h2 __attribute__((ext_vector_type(2)));
typedef _Float16 h4 __attribute__((ext_vector_type(4)));
typedef _Float16 h8 __attribute__((ext_vector_type(8)));
typedef unsigned short us8 __attribute__((ext_vector_type(8)));
typedef __fp16 f16v2 __attribute__((ext_vector_type(2)));
typedef __fp16 f16v8 __attribute__((ext_vector_type(8)));
typedef float f32x4 __attribute__((ext_vector_type(4)));

#define STR1 264     // gl1h/gr1h row stride in halves (528 B, 16B-aligned; 33 h8)
#define STR2H 72     // gl2h/gr2h fp16 row stride in halves (144 B)

#define SV(v, a, b) __builtin_shufflevector(v, v, a, b)

static __device__ __forceinline__ h2 pack_h2(float a, float b) {
    return __builtin_bit_cast(h2, __builtin_amdgcn_cvt_pkrtz(a, b));
}

static __device__ __forceinline__ float fdot2(h2 a, h2 b, float c) {
    return __builtin_amdgcn_fdot2(__builtin_bit_cast(f16v2, a),
                                  __builtin_bit_cast(f16v2, b), c, false);
}

static __device__ __forceinline__ h8 habs8(h8 x) {
    us8 u = __builtin_bit_cast(us8, x);
    us8 m = {0x7fff, 0x7fff, 0x7fff, 0x7fff, 0x7fff, 0x7fff, 0x7fff, 0x7fff};
    return __builtin_bit_cast(h8, (us8)(u & m));
}

static __device__ __forceinline__ f32x4 mfma16(h8 a, h8 b, f32x4 c) {
    return __builtin_amdgcn_mfma_f32_16x16x32_f16(
        __builtin_bit_cast(f16v8, a), __builtin_bit_cast(f16v8, b), c, 0, 0, 0);
}

// ---- pre-pass: pack weights to fp16 ----
// ws h8 segments: [0..2048) Wl2 (MFMA B-frag), [2048..4096) Wr2 (MFMA B-frag),
//   [4096..6144) fc1 [kk][col] (8 x 256)  -- k-major: coalesced when lane=col
//   [6144..14336) fc2 [kk][col] (32 x 256)
__global__ __launch_bounds__(256) void pack_weights_kernel(
    const float* __restrict__ Wl2, const float* __restrict__ Wr2,
    const float* __restrict__ fc1_w, const float* __restrict__ fc2_w,
    h8* __restrict__ ws)
{
    int idx = blockIdx.x * 256 + threadIdx.x;
    if (idx < 4096) {
        const float* W = idx < 2048 ? Wl2 : Wr2;
        int t = idx & 2047;
        int ntile = t >> 9, rem = t & 511;
        int kchunk = rem >> 6, lane = rem & 63;
        int n = ntile * 16 + (lane & 15);
        int k0 = kchunk * 32 + (lane >> 4) * 8;
        h8 o;
        #pragma unroll
        for (int j = 0; j < 8; ++j) o[j] = (_Float16)W[(k0 + j) * 64 + n];
        ws[idx] = o;
    } else if (idx < 6144) {
        int t = idx - 4096;                 // kk-major: t = kk*256 + col
        int kk = t >> 8, col = t & 255;
        h8 o;
        #pragma unroll
        for (int j = 0; j < 8; ++j) o[j] = (_Float16)fc1_w[(kk * 8 + j) * 256 + col];
        ws[idx] = o;
    } else {
        int t = idx - 6144;                 // kk-major: t = kk*256 + col
        int kk = t >> 8, col = t & 255;
        h8 o;
        #pragma unroll
        for (int j = 0; j < 8; ++j) o[j] = (_Float16)fc2_w[(kk * 8 + j) * 256 + col];
        ws[idx] = o;
    }
}

__global__ __launch_bounds__(256, 4) void actor_fused_kernel(
    const float* __restrict__ state24,
    const float* __restrict__ Wl1, const float* __restrict__ Wr1,
    const float* __restrict__ att1, const float* __restrict__ b1,
    const float* __restrict__ att2, const float* __restrict__ b2,
    const float* __restrict__ fc1_b, const float* __restrict__ fc2_b,
    const float* __restrict__ fc3_w, const float* __restrict__ fc3_b,
    const h8* __restrict__ wsL, const h8* __restrict__ wsR,
    const h8* __restrict__ wsF1, const h8* __restrict__ wsF2,
    float* __restrict__ out, int B)
{
    const int bix = blockIdx.x;
    if (bix >= B) return;
    const int tid = threadIdx.x;

    __shared__ float sinL[20], cosL[20], laserL[20], robotL[4];
    __shared__ __align__(16) h2 attLh[128];      // 0.4*att1 fp16 pairs [h][32]
    __shared__ __align__(16) h2 att2Lh[32];      // 0.4*att2 fp16 pairs
    __shared__ __align__(16) _Float16 gr1h[22 * STR1];   // r-transform, then h1 (+zero row 21)
    __shared__ __align__(16) union {
        struct { _Float16 gl1h[22 * STR1];            // +zero row 21
                 float ePf[128 * 24];                  // [h*32+i][24f] -> fp16 A-frag rows
                 float uv[168]; } p1;
        struct { _Float16 gl2h[21 * STR2H];
                 _Float16 gr2h[21 * STR2H];
                 _Float16 gl2hT[64 * 32];             // [col][k]; k>=21 garbage (A k-zeros cover)
                 float e2[32 * 24];                    // logits -> fp16 A-frag; rows 21..31 zero
                 float u2v2[42];
                 _Float16 nfvh[64]; _Float16 hah[256]; _Float16 hbh[256]; } p2;
    } U;

    // ---- setup ----
    if (tid < 20) {
        double step = (PI_D + 0.03) / 20.0;
        float bound = (float)(-PI_D / 2.0 - 0.03 + (double)tid * step);
        float ang = bound + (float)(PI_D / 20.0);
        sinL[tid] = sinf(ang);
        cosL[tid] = cosf(ang);
        laserL[tid] = state24[bix * 24 + tid] * 0.1f;
    }
    if (tid >= 32 && tid < 36) robotL[tid - 32] = state24[bix * 24 + 20 + (tid - 32)];
    if (tid < 128) {
        float2 ap = ((const float2*)att1)[tid];
        attLh[tid] = pack_h2(0.4f * ap.x, 0.4f * ap.y);
    }
    if (tid >= 128 && tid < 160) {
        float2 ap = ((const float2*)att2)[tid - 128];
        att2Lh[tid - 128] = pack_h2(0.4f * ap.x, 0.4f * ap.y);
    }
    __syncthreads();

    // ---- layer-1 transforms -> fp16 LDS + zero gl1h row 21 ----
    {
        h8 zz = {};
        if (tid < 33) ((h8*)U.p1.gl1h)[21 * 33 + tid] = zz;

        const int d2 = tid & 127;      // dims 2*d2, 2*d2+1
        const int half = tid >> 7;     // 0 -> nodes 0..10, 1 -> nodes 11..20
        float2 wl[7], wr[7];
        #pragma unroll
        for (int k = 0; k < 7; k++) {
            wl[k] = ((const float2*)Wl1)[k * 128 + d2];
            wr[k] = ((const float2*)Wr1)[k * 128 + d2];
        }
        const int base = half * 11;
        #pragma unroll
        for (int nn = 0; nn < 11; ++nn) {
            int node = base + nn;
            if (node < 21) {
                float a0, a1, b0, b1v;
                if (node < 20) {
                    float l = laserL[node], s = sinL[node], c = cosL[node];
                    a0 = l * wl[0].x + s * wl[1].x + c * wl[2].x;
                    a1 = l * wl[0].y + s * wl[1].y + c * wl[2].y;
                    b0 = l * wr[0].x + s * wr[1].x + c * wr[2].x;
                    b1v = l * wr[0].y + s * wr[1].y + c * wr[2].y;
                } else {
                    float r0 = robotL[0], r1 = robotL[1], r2 = robotL[2], r3 = robotL[3];
                    a0 = r0 * wl[3].x + r1 * wl[4].x + r2 * wl[5].x + r3 * wl[6].x;
                    a1 = r0 * wl[3].y + r1 * wl[4].y + r2 * wl[5].y + r3 * wl[6].y;
                    b0 = r0 * wr[3].x + r1 * wr[4].x + r2 * wr[5].x + r3 * wr[6].x;
                    b1v = r0 * wr[3].y + r1 * wr[4].y + r2 * wr[5].y + r3 * wr[6].y;
                }
                ((h2*)(U.p1.gl1h + node * STR1))[d2] = pack_h2(a0, a1);
                ((h2*)(gr1h + node * STR1))[d2] = pack_h2(b0, b1v);
            }
        }
    }
    __syncthreads();

    // ---- layer-1 logits (abs part, round-10 indexing) + fused u/v ----
    {
        const int h = tid >> 6;           // wave-uniform head
        const int lane = tid & 63;
        h2 ar[32];
        #pragma unroll
        for (int q = 0; q < 32; ++q) ar[q] = attLh[h * 32 + q];

        for (int it = 0; it < 7; ++it) {
            int q = it * 64 + lane;
            if (q < 441) {
                int i = q / 21;
                int j = q - i * 21;
                const h8* gA8 = (const h8*)(U.p1.gl1h + j * STR1 + h * 64);
                const h8* gB8 = (const h8*)(gr1h + i * STR1 + h * 64);
                float m0 = 0.f, m1 = 0.f;
                #pragma unroll
                for (int ch = 0; ch < 8; ++ch) {
                    h8 x = gA8[ch] + gB8[ch];
                    h8 ax = habs8(x);
                    m0 = fdot2(SV(ax, 0, 1), ar[ch * 4 + 0], m0);
                    m1 = fdot2(SV(ax, 2, 3), ar[ch * 4 + 1], m1);
                    m0 = fdot2(SV(ax, 4, 5), ar[ch * 4 + 2], m0);
                    m1 = fdot2(SV(ax, 6, 7), ar[ch * 4 + 3], m1);
                }
                U.p1.ePf[(h * 32 + i) * 24 + j] = m0 + m1;
            }
        }
        // fused u/v (same inputs as logits; no barrier needed between them)
        if (tid < 168) {
            int r = tid < 84 ? tid : tid - 84;
            int hu = r / 21, idx = r - hu * 21;
            const _Float16* rowp = (tid < 84 ? U.p1.gl1h : gr1h) + idx * STR1 + hu * 64;
            const h8* row8 = (const h8*)rowp;
            const h2* aru = attLh + hu * 32;
            float l0 = 0.f, l1 = 0.f;
            #pragma unroll
            for (int ch = 0; ch < 8; ++ch) {
                h8 g = row8[ch];
                l0 = fdot2(SV(g, 0, 1), aru[ch * 4 + 0], l0);
                l1 = fdot2(SV(g, 2, 3), aru[ch * 4 + 1], l1);
                l0 = fdot2(SV(g, 4, 5), aru[ch * 4 + 2], l0);
                l1 = fdot2(SV(g, 6, 7), aru[ch * 4 + 3], l1);
            }
            U.p1.uv[tid] = l0 + l1;
        }
    }
    __syncthreads();

    // ---- softmax-1 -> fp16 A-frag in place; threads 84..255 zero rows (h, 21..31) ----
    if (tid < 84) {
        int h = tid / 21, i = tid - h * 21;
        int r = h * 32 + i;
        float* row = U.p1.ePf + r * 24;
        const float* uu = U.p1.uv + h * 21;
        float vi = 1.5f * U.p1.uv[84 + h * 21 + i];
        float ebuf[21];
        float m = -1e30f;
        #pragma unroll
        for (int j = 0; j < 21; j++) {
            float e = row[j] + 1.5f * uu[j] + vi;
            ebuf[j] = e;
            m = fmaxf(m, e);
        }
        float s = 0.f;
        #pragma unroll
        for (int j = 0; j < 21; j++) { float v = __expf(ebuf[j] - m); ebuf[j] = v; s += v; }
        float rinv = 1.f / s;
        h8* hp8 = (h8*)(U.p1.ePf) + r * 6;
        h8 o0, o1, o2;
        #pragma unroll
        for (int q = 0; q < 8; ++q) o0[q] = (_Float16)(ebuf[q] * rinv);
        #pragma unroll
        for (int q = 0; q < 8; ++q) o1[q] = (_Float16)(ebuf[8 + q] * rinv);
        #pragma unroll
        for (int q = 0; q < 5; ++q) o2[q] = (_Float16)(ebuf[16 + q] * rinv);
        o2[5] = (_Float16)0.f; o2[6] = (_Float16)0.f; o2[7] = (_Float16)0.f;
        h8 zz = {};
        hp8[0] = o0; hp8[1] = o1; hp8[2] = o2;
        hp8[3] = zz; hp8[4] = zz; hp8[5] = zz;
    } else {
        h8 zz = {};
        for (int z = tid - 84; z < 264; z += 172) {
            int rr = z / 6, slot = z - rr * 6;
            int h = rr / 11, m = 21 + (rr - h * 11);
            ((h8*)U.p1.ePf)[(h * 32 + m) * 6 + slot] = zz;
        }
    }
    __syncthreads();

    // ---- agg1 via MFMA: h1 = P_h @ gl1_h (+bias, ELU -> gr1h) ----
    {
        h8 zz = {};
        if (tid < 33) ((h8*)gr1h)[21 * 33 + tid] = zz;   // zero h1 row 21

        const int lane = tid & 63;
        const int h = tid >> 6;
        const int mcol = lane & 15;
        const int quad = lane >> 4;
        const h8* Af = (const h8*)U.p1.ePf;
        h8 A0 = Af[(h * 32 + mcol) * 6 + quad];
        h8 A1 = Af[(h * 32 + 16 + mcol) * 6 + quad];
        int rowoff[8];
        #pragma unroll
        for (int jj = 0; jj < 8; ++jj) {
            int rr = quad * 8 + jj;
            rowoff[jj] = (rr > 21 ? 21 : rr) * STR1;
        }
        const int colbase = h * 64 + mcol;
        f32x4 z4 = {0.f, 0.f, 0.f, 0.f};
        #pragma unroll
        for (int t = 0; t < 4; ++t) {
            int col = colbase + t * 16;
            h8 bv;
            #pragma unroll
            for (int jj = 0; jj < 8; ++jj) bv[jj] = U.p1.gl1h[rowoff[jj] + col];
            f32x4 d0 = mfma16(A0, bv, z4);
            f32x4 d1 = mfma16(A1, bv, z4);
            float bb = b1[col];
            #pragma unroll
            for (int r = 0; r < 4; ++r) {
                int n0 = quad * 4 + r;
                float v = d0[r] + bb;
                v = v > 0.f ? v : __expf(v) - 1.f;
                gr1h[n0 * STR1 + col] = (_Float16)v;
                int n1 = 16 + quad * 4 + r;
                if (n1 < 21) {
                    float w2 = d1[r] + bb;
                    w2 = w2 > 0.f ? w2 : __expf(w2) - 1.f;
                    gr1h[n1 * STR1 + col] = (_Float16)w2;
                }
            }
        }
    }
    __syncthreads();

    // ---- layer-2 transforms via MFMA; epilogue writes gl2h/gr2h (row) + gl2hT (col) ----
    {
        const int lane = tid & 63;
        const int w = tid >> 6;
        const int mrow = lane & 15;
        const int quad = lane >> 4;
        int rowA1 = 16 + mrow; if (rowA1 > 21) rowA1 = 21;   // rows >=21 are zero
        const h8* hA0 = (const h8*)(gr1h + mrow * STR1 + quad * 8);
        const h8* hA1 = (const h8*)(gr1h + rowA1 * STR1 + quad * 8);
        const h8* bL = wsL + w * 512 + lane;
        const h8* bR = wsR + w * 512 + lane;
        f32x4 aL0 = {0.f, 0.f, 0.f, 0.f}, aL1 = {0.f, 0.f, 0.f, 0.f};
        f32x4 aR0 = {0.f, 0.f, 0.f, 0.f}, aR1 = {0.f, 0.f, 0.f, 0.f};
        #pragma unroll
        for (int kc = 0; kc < 8; ++kc) {
            h8 A0 = hA0[kc * 4];
            h8 A1 = hA1[kc * 4];
            h8 BL = bL[kc * 64];
            h8 BR = bR[kc * 64];
            aL0 = mfma16(A0, BL, aL0);
            aL1 = mfma16(A1, BL, aL1);
            aR0 = mfma16(A0, BR, aR0);
            aR1 = mfma16(A1, BR, aR1);
        }
        const int col = w * 16 + mrow;
        #pragma unroll
        for (int r = 0; r < 4; ++r) {
            int row0 = quad * 4 + r;
            U.p2.gl2h[row0 * STR2H + col] = (_Float16)aL0[r];
            U.p2.gr2h[row0 * STR2H + col] = (_Float16)aR0[r];
            int row1 = 16 + row0;
            if (row1 < 21) {
                U.p2.gl2h[row1 * STR2H + col] = (_Float16)aL1[r];
                U.p2.gr2h[row1 * STR2H + col] = (_Float16)aR1[r];
            }
        }
        // transposed L: gl2hT[col][k]; k>=21 garbage is covered by e2's A k-zeros
        {
            h2 lo0 = pack_h2(aL0[0], aL0[1]);
            h2 hi0 = pack_h2(aL0[2], aL0[3]);
            h4 p0 = __builtin_shufflevector(lo0, hi0, 0, 1, 2, 3);
            *(h4*)(U.p2.gl2hT + col * 32 + quad * 4) = p0;
            h2 lo1 = pack_h2(aL1[0], aL1[1]);
            h2 hi1 = pack_h2(aL1[2], aL1[3]);
            h4 p1 = __builtin_shufflevector(lo1, hi1, 0, 1, 2, 3);
            *(h4*)(U.p2.gl2hT + col * 32 + 16 + quad * 4) = p1;
        }
    }
    __syncthreads();

    // ---- layer-2 logits (abs part, fp16) + u2/v2 in spare slots ----
    {
        h2 ar2[32];
        #pragma unroll
        for (int q = 0; q < 32; ++q) ar2[q] = att2Lh[q];

        #pragma unroll
        for (int it = 0; it < 2; ++it) {
            int t = it * 256 + tid;
            if (t < 441) {
                int i = t / 21;
                int j = t - i * 21;
                const h8* gA8 = (const h8*)(U.p2.gl2h + j * STR2H);
                const h8* gB8 = (const h8*)(U.p2.gr2h + i * STR2H);
                float m0 = 0.f, m1 = 0.f;
                #pragma unroll
                for (int ch = 0; ch < 8; ++ch) {
                    h8 x = gA8[ch] + gB8[ch];
                    h8 ax = habs8(x);
                    m0 = fdot2(SV(ax, 0, 1), ar2[ch * 4 + 0], m0);
                    m1 = fdot2(SV(ax, 2, 3), ar2[ch * 4 + 1], m1);
                    m0 = fdot2(SV(ax, 4, 5), ar2[ch * 4 + 2], m0);
                    m1 = fdot2(SV(ax, 6, 7), ar2[ch * 4 + 3], m1);
                }
                U.p2.e2[i * 24 + j] = m0 + m1;
            } else if (t < 483) {
                int u = t - 441;                  // 0..41
                int r = u < 21 ? u : u - 21;
                const _Float16* rowp = (u < 21 ? U.p2.gl2h : U.p2.gr2h) + r * STR2H;
                const h8* row8 = (const h8*)rowp;
                float l0 = 0.f, l1 = 0.f;
                #pragma unroll
                for (int ch = 0; ch < 8; ++ch) {
                    h8 g = row8[ch];
                    l0 = fdot2(SV(g, 0, 1), ar2[ch * 4 + 0], l0);
                    l1 = fdot2(SV(g, 2, 3), ar2[ch * 4 + 1], l1);
                    l0 = fdot2(SV(g, 4, 5), ar2[ch * 4 + 2], l0);
                    l1 = fdot2(SV(g, 6, 7), ar2[ch * 4 + 3], l1);
                }
                U.p2.u2v2[u] = l0 + l1;
            }
        }
    }
    __syncthreads();

    // ---- softmax-2 -> fp16 A-frag in place; zero rows 21..31 ----
    if (tid < 21) {
        float* row = U.p2.e2 + tid * 24;
        const float* uu = U.p2.u2v2;
        float vi = 1.5f * U.p2.u2v2[21 + tid];
        float ebuf[21];
        float m = -1e30f;
        #pragma unroll
        for (int j = 0; j < 21; j++) {
            float e = row[j] + 1.5f * uu[j] + vi;
            ebuf[j] = e;
            m = fmaxf(m, e);
        }
        float s = 0.f;
        #pragma unroll
        for (int j = 0; j < 21; j++) { float v = __expf(ebuf[j] - m); ebuf[j] = v; s += v; }
        float rinv = 1.f / s;
        h8* hp8 = (h8*)(U.p2.e2) + tid * 6;
        h8 o0, o1, o2;
        #pragma unroll
        for (int q = 0; q < 8; ++q) o0[q] = (_Float16)(ebuf[q] * rinv);
        #pragma unroll
        for (int q = 0; q < 8; ++q) o1[q] = (_Float16)(ebuf[8 + q] * rinv);
        #pragma unroll
        for (int q = 0; q < 5; ++q) o2[q] = (_Float16)(ebuf[16 + q] * rinv);
        o2[5] = (_Float16)0.f; o2[6] = (_Float16)0.f; o2[7] = (_Float16)0.f;
        h8 zz = {};
        hp8[0] = o0; hp8[1] = o1; hp8[2] = o2;
        hp8[3] = zz; hp8[4] = zz; hp8[5] = zz;
    } else if (tid < 87) {
        int z = tid - 21;
        int rr = z / 6, slot = z - rr * 6;
        h8 zz = {};
        ((h8*)U.p2.e2)[(21 + rr) * 6 + slot] = zz;
    }
    __syncthreads();

    // ---- agg2 + mean-pool via MFMA -> nfvh direct ----
    {
        const int lane = tid & 63;
        const int w = tid >> 6;           // ntile
        const int mcol = lane & 15;
        const int quad = lane >> 4;
        const h8* Af2 = (const h8*)U.p2.e2;
        h8 A0 = Af2[mcol * 6 + quad];
        h8 A1 = Af2[(16 + mcol) * 6 + quad];   // rows 21..31 true zeros
        h8 bv = *(const h8*)(U.p2.gl2hT + (w * 16 + mcol) * 32 + quad * 8);
        f32x4 z4 = {0.f, 0.f, 0.f, 0.f};
        f32x4 d0 = mfma16(A0, bv, z4);
        f32x4 d1 = mfma16(A1, bv, z4);
        float s = (d0[0] + d0[1]) + (d0[2] + d0[3])
                + (d1[0] + d1[1]) + (d1[2] + d1[3]);
        s += __shfl_xor(s, 16, 64);
        s += __shfl_xor(s, 32, 64);
        if (quad == 0) {
            int col = w * 16 + mcol;
            U.p2.nfvh[col] = (_Float16)(s * (1.f / 21.f) + b2[col]);
        }
    }
    __syncthreads();

    // ---- FC1 (64 -> 256): coalesced [kk][col] weights, no reduction ----
    {
        const h8* nf8 = (const h8*)U.p2.nfvh;
        float a0 = 0.f, a1 = 0.f, a2 = 0.f, a3 = 0.f;
        #pragma unroll
        for (int kk = 0; kk < 8; ++kk) {
            h8 w = wsF1[kk * 256 + tid];    // lane=col: consecutive 16 B
            h8 xa = nf8[kk];                // LDS broadcast
            a0 = fdot2(SV(w, 0, 1), SV(xa, 0, 1), a0);
            a1 = fdot2(SV(w, 2, 3), SV(xa, 2, 3), a1);
            a2 = fdot2(SV(w, 4, 5), SV(xa, 4, 5), a2);
            a3 = fdot2(SV(w, 6, 7), SV(xa, 6, 7), a3);
        }
        float v = (a0 + a1) + (a2 + a3) + fc1_b[tid];
        U.p2.hah[tid] = (_Float16)fmaxf(v, 0.f);
    }
    __syncthreads();

    // ---- FC2 (256 -> 256): coalesced [kk][col] weights, no reduction ----
    {
        const h8* ha8 = (const h8*)U.p2.hah;
        float a0 = 0.f, a1 = 0.f, a2 = 0.f, a3 = 0.f;
        #pragma unroll 8
        for (int kk = 0; kk < 32; ++kk) {
            h8 w = wsF2[kk * 256 + tid];    // coalesced
            h8 xa = ha8[kk];                // LDS broadcast
            a0 = fdot2(SV(w, 0, 1), SV(xa, 0, 1), a0);
            a1 = fdot2(SV(w, 2, 3), SV(xa, 2, 3), a1);
            a2 = fdot2(SV(w, 4, 5), SV(xa, 4, 5), a2);
            a3 = fdot2(SV(w, 6, 7), SV(xa, 6, 7), a3);
        }
        float v = (a0 + a1) + (a2 + a3) + fc2_b[tid];
        U.p2.hbh[tid] = (_Float16)fmaxf(v, 0.f);
    }
    __syncthreads();

    // ---- FC3 (256 -> 2) + tanh ----
    if (tid < 128) {
        int o = tid >> 6, l = tid & 63;
        float s = 0.f;
        #pragma unroll
        for (int m = 0; m < 4; m++) {
            int k = l + 64 * m;
            s = fmaf((float)U.p2.hbh[k], fc3_w[k * 2 + o], s);
        }
        #pragma unroll
        for (int off = 32; off >= 1; off >>= 1) s += __shfl_down(s, off, 64);
        if (l == 0) out[bix * 2 + o] = tanhf(s + fc3_b[o]);
    }
}

extern "C" void kernel_launch(void* const* d_in, const int* in_sizes, int n_in,
                              void* d_out, int out_size, void* d_ws, size_t ws_size,
                              hipStream_t stream) {
    const float* state24 = (const float*)d_in[0];
    const float* Wl1 = (const float*)d_in[1];
    const float* Wr1 = (const float*)d_in[2];
    const float* att1 = (const float*)d_in[3];
    const float* b1 = (const float*)d_in[4];
    const float* Wl2 = (const float*)d_in[5];
    const float* Wr2 = (const float*)d_in[6];
    const float* att2 = (const float*)d_in[7];
    const float* b2 = (const float*)d_in[8];
    const float* fc1_w = (const float*)d_in[9];
    const float* fc1_b = (const float*)d_in[10];
    const float* fc2_w = (const float*)d_in[11];
    const float* fc2_b = (const float*)d_in[12];
    const float* fc3_w = (const float*)d_in[13];
    const float* fc3_b = (const float*)d_in[14];
    float* out = (float*)d_out;

    h8* ws = (h8*)d_ws;                 // 14336 h8 = 224 KiB
    const h8* wsL = ws;
    const h8* wsR = ws + 2048;
    const h8* wsF1 = ws + 4096;
    const h8* wsF2 = ws + 6144;

    pack_weights_kernel<<<56, 256, 0, stream>>>(Wl2, Wr2, fc1_w, fc2_w, ws);

    int B = in_sizes[0] / 24;
    actor_fused_kernel<<<B, 256, 0, stream>>>(
        state24, Wl1, Wr1, att1, b1, att2, b2,
        fc1_b, fc2_b, fc3_w, fc3_b,
        wsL, wsR, wsF1, wsF2, out, B);
}

// Round 13
// 113.649 us; speedup vs baseline: 1.1181x; 1.1168x over previous
//
#include <hip/hip_runtime.h>
#include <hip/hip_fp16.h>
#include <math.h>

#define PI_D 3.141592653589793

typedef _Float16 h2 __attribute__((ext_vector_type(2)));
typedef _Float16 h4 __attribute__((ext_vector_type(4)));
typedef _Float16 h8 __attribute__((ext_vector_type(8)));
typedef unsigned short us8 __attribute__((ext_vector_type(8)));
typedef __fp16 f16v2 __attribute__((ext_vector_type(2)));
typedef __fp16 f16v8 __attribute__((ext_vector_type(8)));
typedef float f32x4 __attribute__((ext_vector_type(4)));

#define STR1 264     // gl1h/gr1h row stride in halves (528 B, 16B-aligned; 33 h8)
#define STR2H 72     // gl2h/gr2h fp16 row stride in halves (144 B)

#define SV(v, a, b) __builtin_shufflevector(v, v, a, b)

static __device__ __forceinline__ h2 pack_h2(float a, float b) {
    return __builtin_bit_cast(h2, __builtin_amdgcn_cvt_pkrtz(a, b));
}

static __device__ __forceinline__ float fdot2(h2 a, h2 b, float c) {
    return __builtin_amdgcn_fdot2(__builtin_bit_cast(f16v2, a),
                                  __builtin_bit_cast(f16v2, b), c, false);
}

static __device__ __forceinline__ h8 habs8(h8 x) {
    us8 u = __builtin_bit_cast(us8, x);
    us8 m = {0x7fff, 0x7fff, 0x7fff, 0x7fff, 0x7fff, 0x7fff, 0x7fff, 0x7fff};
    return __builtin_bit_cast(h8, (us8)(u & m));
}

static __device__ __forceinline__ f32x4 mfma16(h8 a, h8 b, f32x4 c) {
    return __builtin_amdgcn_mfma_f32_16x16x32_f16(
        __builtin_bit_cast(f16v8, a), __builtin_bit_cast(f16v8, b), c, 0, 0, 0);
}

// wave-private phase separator: pins compiler ordering; HW LDS is in-order per wave
static __device__ __forceinline__ void wave_fence() {
    asm volatile("" ::: "memory");
#if __has_builtin(__builtin_amdgcn_wave_barrier)
    __builtin_amdgcn_wave_barrier();
#endif
    asm volatile("" ::: "memory");
}

// ---- pre-pass: pack weights to fp16 (round-10 layouts) ----
// ws h8 segments: [0..2048) Wl2 (MFMA B-frag), [2048..4096) Wr2 (MFMA B-frag),
//                 [4096..6144) fc1, [6144..14336) fc2
__global__ __launch_bounds__(256) void pack_weights_kernel(
    const float* __restrict__ Wl2, const float* __restrict__ Wr2,
    const float* __restrict__ fc1_w, const float* __restrict__ fc2_w,
    h8* __restrict__ ws)
{
    int idx = blockIdx.x * 256 + threadIdx.x;
    if (idx < 4096) {
        const float* W = idx < 2048 ? Wl2 : Wr2;
        int t = idx & 2047;
        int ntile = t >> 9, rem = t & 511;
        int kchunk = rem >> 6, lane = rem & 63;
        int n = ntile * 16 + (lane & 15);
        int k0 = kchunk * 32 + (lane >> 4) * 8;
        h8 o;
        #pragma unroll
        for (int j = 0; j < 8; ++j) o[j] = (_Float16)W[(k0 + j) * 64 + n];
        ws[idx] = o;
    } else if (idx < 6144) {
        int t = idx - 4096;
        int k2 = t >> 6, c = t & 63;
        h8 o;
        #pragma unroll
        for (int q = 0; q < 4; ++q) {
            o[2 * q]     = (_Float16)fc1_w[(2 * k2) * 256 + 4 * c + q];
            o[2 * q + 1] = (_Float16)fc1_w[(2 * k2 + 1) * 256 + 4 * c + q];
        }
        ws[idx] = o;
    } else {
        int t = idx - 6144;
        int k2 = t >> 6, c = t & 63;
        h8 o;
        #pragma unroll
        for (int q = 0; q < 4; ++q) {
            o[2 * q]     = (_Float16)fc2_w[(2 * k2) * 256 + 4 * c + q];
            o[2 * q + 1] = (_Float16)fc2_w[(2 * k2 + 1) * 256 + 4 * c + q];
        }
        ws[idx] = o;
    }
}

__global__ __launch_bounds__(256, 4) void actor_fused_kernel(
    const float* __restrict__ state24,
    const float* __restrict__ Wl1, const float* __restrict__ Wr1,
    const float* __restrict__ att1, const float* __restrict__ b1,
    const float* __restrict__ att2, const float* __restrict__ b2,
    const float* __restrict__ fc1_b, const float* __restrict__ fc2_b,
    const float* __restrict__ fc3_w, const float* __restrict__ fc3_b,
    const h8* __restrict__ wsL, const h8* __restrict__ wsR,
    const h8* __restrict__ wsF1, const h8* __restrict__ wsF2,
    float* __restrict__ out, int B)
{
    const int bix = blockIdx.x;
    if (bix >= B) return;
    const int tid = threadIdx.x;

    __shared__ float sinL[20], cosL[20], laserL[20], robotL[4];
    __shared__ __align__(16) h2 attLh[128];      // 0.4*att1 fp16 pairs [h][32]
    __shared__ __align__(16) h2 att2Lh[32];      // 0.4*att2 fp16 pairs
    __shared__ __align__(16) _Float16 gr1h[22 * STR1];   // r-transform, then h1 (+zero row 21)
    __shared__ __align__(16) union {
        struct { _Float16 gl1h[22 * STR1];            // +zero row 21
                 float ePf[128 * 24];                  // [h*32+i][24f] -> fp16 A-frag rows
                 float uv[168]; } p1;
        struct { _Float16 gl2h[21 * STR2H];
                 _Float16 gr2h[21 * STR2H];
                 _Float16 gl2hT[64 * 32];             // [col][k]; k>=21 garbage (A k-zeros cover)
                 float e2[32 * 24];                    // logits -> fp16 A-frag; rows 21..31 zero
                 float u2v2[42];
                 float red[4][256];
                 _Float16 nfvh[64]; _Float16 hah[256]; _Float16 hbh[256]; } p2;
    } U;

    // ---- setup ----
    if (tid < 20) {
        double step = (PI_D + 0.03) / 20.0;
        float bound = (float)(-PI_D / 2.0 - 0.03 + (double)tid * step);
        float ang = bound + (float)(PI_D / 20.0);
        sinL[tid] = sinf(ang);
        cosL[tid] = cosf(ang);
        laserL[tid] = state24[bix * 24 + tid] * 0.1f;
    }
    if (tid >= 32 && tid < 36) robotL[tid - 32] = state24[bix * 24 + 20 + (tid - 32)];
    if (tid < 128) {
        float2 ap = ((const float2*)att1)[tid];
        attLh[tid] = pack_h2(0.4f * ap.x, 0.4f * ap.y);
    }
    if (tid >= 128 && tid < 160) {
        float2 ap = ((const float2*)att2)[tid - 128];
        att2Lh[tid - 128] = pack_h2(0.4f * ap.x, 0.4f * ap.y);
    }
    __syncthreads();

    // ================= L1 block: wave h owns head h — NO cross-wave deps =================
    {
        const int h = tid >> 6;
        const int lane = tid & 63;

        // ---- transform1 (wave-private): lane owns column-pair cp of head h ----
        {
            const int cp = lane & 31;          // column pair within head
            const int half = lane >> 5;        // 0: nodes 0..10, 1: nodes 11..20
            const int d2 = h * 32 + cp;        // float2 index (dims 2*d2, 2*d2+1)
            float2 wl[7], wr[7];
            #pragma unroll
            for (int k = 0; k < 7; k++) {
                wl[k] = ((const float2*)Wl1)[k * 128 + d2];
                wr[k] = ((const float2*)Wr1)[k * 128 + d2];
            }
            if (half == 0) {                   // zero row 21 of own columns (both arrays)
                h2 zz2 = {};
                ((h2*)(U.p1.gl1h + 21 * STR1))[d2] = zz2;
                ((h2*)(gr1h + 21 * STR1))[d2] = zz2;
            }
            const int base = half * 11;
            #pragma unroll
            for (int nn = 0; nn < 11; ++nn) {
                int node = base + nn;
                if (node < 21) {
                    float a0, a1, b0, b1v;
                    if (node < 20) {
                        float l = laserL[node], s = sinL[node], c = cosL[node];
                        a0 = l * wl[0].x + s * wl[1].x + c * wl[2].x;
                        a1 = l * wl[0].y + s * wl[1].y + c * wl[2].y;
                        b0 = l * wr[0].x + s * wr[1].x + c * wr[2].x;
                        b1v = l * wr[0].y + s * wr[1].y + c * wr[2].y;
                    } else {
                        float r0 = robotL[0], r1 = robotL[1], r2 = robotL[2], r3 = robotL[3];
                        a0 = r0 * wl[3].x + r1 * wl[4].x + r2 * wl[5].x + r3 * wl[6].x;
                        a1 = r0 * wl[3].y + r1 * wl[4].y + r2 * wl[5].y + r3 * wl[6].y;
                        b0 = r0 * wr[3].x + r1 * wr[4].x + r2 * wr[5].x + r3 * wr[6].x;
                        b1v = r0 * wr[3].y + r1 * wr[4].y + r2 * wr[5].y + r3 * wr[6].y;
                    }
                    ((h2*)(U.p1.gl1h + node * STR1))[d2] = pack_h2(a0, a1);
                    ((h2*)(gr1h + node * STR1))[d2] = pack_h2(b0, b1v);
                }
            }
        }
        wave_fence();

        // ---- logits1 (abs part) + u/v, all wave-private; att in registers ----
        {
            h2 ar[32];
            #pragma unroll
            for (int q = 0; q < 32; ++q) ar[q] = attLh[h * 32 + q];

            for (int it = 0; it < 7; ++it) {
                int q = it * 64 + lane;
                if (q < 441) {
                    int i = q / 21;
                    int j = q - i * 21;
                    const h8* gA8 = (const h8*)(U.p1.gl1h + j * STR1 + h * 64);
                    const h8* gB8 = (const h8*)(gr1h + i * STR1 + h * 64);
                    float m0 = 0.f, m1 = 0.f;
                    #pragma unroll
                    for (int ch = 0; ch < 8; ++ch) {
                        h8 x = gA8[ch] + gB8[ch];
                        h8 ax = habs8(x);
                        m0 = fdot2(SV(ax, 0, 1), ar[ch * 4 + 0], m0);
                        m1 = fdot2(SV(ax, 2, 3), ar[ch * 4 + 1], m1);
                        m0 = fdot2(SV(ax, 4, 5), ar[ch * 4 + 2], m0);
                        m1 = fdot2(SV(ax, 6, 7), ar[ch * 4 + 3], m1);
                    }
                    U.p1.ePf[(h * 32 + i) * 24 + j] = m0 + m1;
                }
            }
            if (lane < 42) {
                int isV = lane >= 21;
                int idx = isV ? lane - 21 : lane;
                const _Float16* rowp = (isV ? (const _Float16*)gr1h
                                            : (const _Float16*)U.p1.gl1h) + idx * STR1 + h * 64;
                const h8* row8 = (const h8*)rowp;
                float l0 = 0.f, l1 = 0.f;
                #pragma unroll
                for (int ch = 0; ch < 8; ++ch) {
                    h8 g = row8[ch];
                    l0 = fdot2(SV(g, 0, 1), ar[ch * 4 + 0], l0);
                    l1 = fdot2(SV(g, 2, 3), ar[ch * 4 + 1], l1);
                    l0 = fdot2(SV(g, 4, 5), ar[ch * 4 + 2], l0);
                    l1 = fdot2(SV(g, 6, 7), ar[ch * 4 + 3], l1);
                }
                U.p1.uv[(isV ? 84 : 0) + h * 21 + idx] = l0 + l1;
            }
        }
        wave_fence();

        // ---- softmax1 (wave-private): lane<21 -> row (h,lane); zero rows 21..31 ----
        if (lane < 21) {
            int r = h * 32 + lane;
            float* row = U.p1.ePf + r * 24;
            const float* uu = U.p1.uv + h * 21;
            float vi = 1.5f * U.p1.uv[84 + h * 21 + lane];
            float ebuf[21];
            float m = -1e30f;
            #pragma unroll
            for (int j = 0; j < 21; j++) {
                float e = row[j] + 1.5f * uu[j] + vi;
                ebuf[j] = e;
                m = fmaxf(m, e);
            }
            float s = 0.f;
            #pragma unroll
            for (int j = 0; j < 21; j++) { float v = __expf(ebuf[j] - m); ebuf[j] = v; s += v; }
            float rinv = 1.f / s;
            h8* hp8 = (h8*)(U.p1.ePf) + r * 6;
            h8 o0, o1, o2;
            #pragma unroll
            for (int q = 0; q < 8; ++q) o0[q] = (_Float16)(ebuf[q] * rinv);
            #pragma unroll
            for (int q = 0; q < 8; ++q) o1[q] = (_Float16)(ebuf[8 + q] * rinv);
            #pragma unroll
            for (int q = 0; q < 5; ++q) o2[q] = (_Float16)(ebuf[16 + q] * rinv);
            o2[5] = (_Float16)0.f; o2[6] = (_Float16)0.f; o2[7] = (_Float16)0.f;
            h8 zz = {};
            hp8[0] = o0; hp8[1] = o1; hp8[2] = o2;
            hp8[3] = zz; hp8[4] = zz; hp8[5] = zz;
        }
        {   // zero fp16 A-frag rows (h, 21..31): 66 h8 slots per head
            h8 zz = {};
            for (int z = lane; z < 66; z += 64) {
                int rr = z / 6, slot = z - rr * 6;
                ((h8*)U.p1.ePf)[(h * 32 + 21 + rr) * 6 + slot] = zz;
            }
        }
        wave_fence();

        // ---- agg1 via MFMA (wave-private): h1 = P_h @ gl1_h (+bias, ELU -> gr1h) ----
        {
            const int mcol = lane & 15;
            const int quad = lane >> 4;
            const h8* Af = (const h8*)U.p1.ePf;
            h8 A0 = Af[(h * 32 + mcol) * 6 + quad];
            h8 A1 = Af[(h * 32 + 16 + mcol) * 6 + quad];
            int rowoff[8];
            #pragma unroll
            for (int jj = 0; jj < 8; ++jj) {
                int rr = quad * 8 + jj;
                rowoff[jj] = (rr > 21 ? 21 : rr) * STR1;
            }
            const int colbase = h * 64 + mcol;
            f32x4 z4 = {0.f, 0.f, 0.f, 0.f};
            #pragma unroll
            for (int t = 0; t < 4; ++t) {
                int col = colbase + t * 16;
                h8 bv;
                #pragma unroll
                for (int jj = 0; jj < 8; ++jj) bv[jj] = U.p1.gl1h[rowoff[jj] + col];
                f32x4 d0 = mfma16(A0, bv, z4);
                f32x4 d1 = mfma16(A1, bv, z4);
                float bb = b1[col];
                #pragma unroll
                for (int r = 0; r < 4; ++r) {
                    int n0 = quad * 4 + r;
                    float v = d0[r] + bb;
                    v = v > 0.f ? v : __expf(v) - 1.f;
                    gr1h[n0 * STR1 + col] = (_Float16)v;
                    int n1 = 16 + quad * 4 + r;
                    if (n1 < 21) {
                        float w2 = d1[r] + bb;
                        w2 = w2 > 0.f ? w2 : __expf(w2) - 1.f;
                        gr1h[n1 * STR1 + col] = (_Float16)w2;
                    }
                }
            }
        }
    }
    __syncthreads();
    // ================= end L1 block =================

    // ---- layer-2 transforms via MFMA; epilogue writes gl2h/gr2h (row) + gl2hT (col) ----
    {
        const int lane = tid & 63;
        const int w = tid >> 6;
        const int mrow = lane & 15;
        const int quad = lane >> 4;
        int rowA1 = 16 + mrow; if (rowA1 > 21) rowA1 = 21;   // rows >=21 are zero
        const h8* hA0 = (const h8*)(gr1h + mrow * STR1 + quad * 8);
        const h8* hA1 = (const h8*)(gr1h + rowA1 * STR1 + quad * 8);
        const h8* bL = wsL + w * 512 + lane;
        const h8* bR = wsR + w * 512 + lane;
        f32x4 aL0 = {0.f, 0.f, 0.f, 0.f}, aL1 = {0.f, 0.f, 0.f, 0.f};
        f32x4 aR0 = {0.f, 0.f, 0.f, 0.f}, aR1 = {0.f, 0.f, 0.f, 0.f};
        #pragma unroll
        for (int kc = 0; kc < 8; ++kc) {
            h8 A0 = hA0[kc * 4];
            h8 A1 = hA1[kc * 4];
            h8 BL = bL[kc * 64];
            h8 BR = bR[kc * 64];
            aL0 = mfma16(A0, BL, aL0);
            aL1 = mfma16(A1, BL, aL1);
            aR0 = mfma16(A0, BR, aR0);
            aR1 = mfma16(A1, BR, aR1);
        }
        const int col = w * 16 + mrow;
        #pragma unroll
        for (int r = 0; r < 4; ++r) {
            int row0 = quad * 4 + r;
            U.p2.gl2h[row0 * STR2H + col] = (_Float16)aL0[r];
            U.p2.gr2h[row0 * STR2H + col] = (_Float16)aR0[r];
            int row1 = 16 + row0;
            if (row1 < 21) {
                U.p2.gl2h[row1 * STR2H + col] = (_Float16)aL1[r];
                U.p2.gr2h[row1 * STR2H + col] = (_Float16)aR1[r];
            }
        }
        // transposed L: gl2hT[col][k]; k>=21 garbage covered by e2's A k-zeros
        {
            h2 lo0 = pack_h2(aL0[0], aL0[1]);
            h2 hi0 = pack_h2(aL0[2], aL0[3]);
            h4 p0 = __builtin_shufflevector(lo0, hi0, 0, 1, 2, 3);
            *(h4*)(U.p2.gl2hT + col * 32 + quad * 4) = p0;
            h2 lo1 = pack_h2(aL1[0], aL1[1]);
            h2 hi1 = pack_h2(aL1[2], aL1[3]);
            h4 p1 = __builtin_shufflevector(lo1, hi1, 0, 1, 2, 3);
            *(h4*)(U.p2.gl2hT + col * 32 + 16 + quad * 4) = p1;
        }
    }
    __syncthreads();

    // ---- layer-2 logits (abs part, fp16) + u2/v2 in spare slots ----
    {
        h2 ar2[32];
        #pragma unroll
        for (int q = 0; q < 32; ++q) ar2[q] = att2Lh[q];

        #pragma unroll
        for (int it = 0; it < 2; ++it) {
            int t = it * 256 + tid;
            if (t < 441) {
                int i = t / 21;
                int j = t - i * 21;
                const h8* gA8 = (const h8*)(U.p2.gl2h + j * STR2H);
                const h8* gB8 = (const h8*)(U.p2.gr2h + i * STR2H);
                float m0 = 0.f, m1 = 0.f;
                #pragma unroll
                for (int ch = 0; ch < 8; ++ch) {
                    h8 x = gA8[ch] + gB8[ch];
                    h8 ax = habs8(x);
                    m0 = fdot2(SV(ax, 0, 1), ar2[ch * 4 + 0], m0);
                    m1 = fdot2(SV(ax, 2, 3), ar2[ch * 4 + 1], m1);
                    m0 = fdot2(SV(ax, 4, 5), ar2[ch * 4 + 2], m0);
                    m1 = fdot2(SV(ax, 6, 7), ar2[ch * 4 + 3], m1);
                }
                U.p2.e2[i * 24 + j] = m0 + m1;
            } else if (t < 483) {
                int u = t - 441;                  // 0..41
                int r = u < 21 ? u : u - 21;
                const _Float16* rowp = (u < 21 ? U.p2.gl2h : U.p2.gr2h) + r * STR2H;
                const h8* row8 = (const h8*)rowp;
                float l0 = 0.f, l1 = 0.f;
                #pragma unroll
                for (int ch = 0; ch < 8; ++ch) {
                    h8 g = row8[ch];
                    l0 = fdot2(SV(g, 0, 1), ar2[ch * 4 + 0], l0);
                    l1 = fdot2(SV(g, 2, 3), ar2[ch * 4 + 1], l1);
                    l0 = fdot2(SV(g, 4, 5), ar2[ch * 4 + 2], l0);
                    l1 = fdot2(SV(g, 6, 7), ar2[ch * 4 + 3], l1);
                }
                U.p2.u2v2[u] = l0 + l1;
            }
        }
    }
    __syncthreads();

    // ---- softmax-2 -> fp16 A-frag in place; zero rows 21..31 ----
    if (tid < 21) {
        float* row = U.p2.e2 + tid * 24;
        const float* uu = U.p2.u2v2;
        float vi = 1.5f * U.p2.u2v2[21 + tid];
        float ebuf[21];
        float m = -1e30f;
        #pragma unroll
        for (int j = 0; j < 21; j++) {
            float e = row[j] + 1.5f * uu[j] + vi;
            ebuf[j] = e;
            m = fmaxf(m, e);
        }
        float s = 0.f;
        #pragma unroll
        for (int j = 0; j < 21; j++) { float v = __expf(ebuf[j] - m); ebuf[j] = v; s += v; }
        float rinv = 1.f / s;
        h8* hp8 = (h8*)(U.p2.e2) + tid * 6;
        h8 o0, o1, o2;
        #pragma unroll
        for (int q = 0; q < 8; ++q) o0[q] = (_Float16)(ebuf[q] * rinv);
        #pragma unroll
        for (int q = 0; q < 8; ++q) o1[q] = (_Float16)(ebuf[8 + q] * rinv);
        #pragma unroll
        for (int q = 0; q < 5; ++q) o2[q] = (_Float16)(ebuf[16 + q] * rinv);
        o2[5] = (_Float16)0.f; o2[6] = (_Float16)0.f; o2[7] = (_Float16)0.f;
        h8 zz = {};
        hp8[0] = o0; hp8[1] = o1; hp8[2] = o2;
        hp8[3] = zz; hp8[4] = zz; hp8[5] = zz;
    } else if (tid < 87) {
        int z = tid - 21;
        int rr = z / 6, slot = z - rr * 6;
        h8 zz = {};
        ((h8*)U.p2.e2)[(21 + rr) * 6 + slot] = zz;
    }
    __syncthreads();

    // ---- agg2 + mean-pool via MFMA -> nfvh direct ----
    {
        const int lane = tid & 63;
        const int w = tid >> 6;           // ntile
        const int mcol = lane & 15;
        const int quad = lane >> 4;
        const h8* Af2 = (const h8*)U.p2.e2;
        h8 A0 = Af2[mcol * 6 + quad];
        h8 A1 = Af2[(16 + mcol) * 6 + quad];   // rows 21..31 true zeros
        h8 bv = *(const h8*)(U.p2.gl2hT + (w * 16 + mcol) * 32 + quad * 8);
        f32x4 z4 = {0.f, 0.f, 0.f, 0.f};
        f32x4 d0 = mfma16(A0, bv, z4);
        f32x4 d1 = mfma16(A1, bv, z4);
        float s = (d0[0] + d0[1]) + (d0[2] + d0[3])
                + (d1[0] + d1[1]) + (d1[2] + d1[3]);
        s += __shfl_xor(s, 16, 64);
        s += __shfl_xor(s, 32, 64);
        if (quad == 0) {
            int col = w * 16 + mcol;
            U.p2.nfvh[col] = (_Float16)(s * (1.f / 21.f) + b2[col]);
        }
    }
    __syncthreads();

    // ---- FC1 (64 -> 256): fp16 packed weights (round-10 form) ----
    {
        int c = tid & 63, g = tid >> 6;
        const h2* x2p = (const h2*)U.p2.nfvh;
        float4 acc = {0.f, 0.f, 0.f, 0.f};
        #pragma unroll
        for (int kk = 0; kk < 8; ++kk) {
            int k2 = g * 8 + kk;
            h8 w = wsF1[k2 * 64 + c];
            h2 x2 = x2p[k2];
            acc.x = fdot2(SV(w, 0, 1), x2, acc.x);
            acc.y = fdot2(SV(w, 2, 3), x2, acc.y);
            acc.z = fdot2(SV(w, 4, 5), x2, acc.z);
            acc.w = fdot2(SV(w, 6, 7), x2, acc.w);
        }
        ((float4*)U.p2.red[g])[c] = acc;
    }
    __syncthreads();
    {
        float v = U.p2.red[0][tid] + U.p2.red[1][tid] + U.p2.red[2][tid] + U.p2.red[3][tid]
                  + fc1_b[tid];
        U.p2.hah[tid] = (_Float16)fmaxf(v, 0.f);
    }
    __syncthreads();

    // ---- FC2 (256 -> 256): fp16 packed weights + fp16 activations (round-10 form) ----
    {
        int c = tid & 63, g = tid >> 6;
        const h8* haH = (const h8*)U.p2.hah;
        float4 acc = {0.f, 0.f, 0.f, 0.f};
#define FC2_STEP(q, p)                                                          \
        {                                                                       \
            int k2 = g * 32 + (q) * 4 + (p);                                    \
            h8 w = wsF2[k2 * 64 + c];                                           \
            h2 x2 = __builtin_shufflevector(xa, xa, 2 * (p), 2 * (p) + 1);      \
            acc.x = fdot2(SV(w, 0, 1), x2, acc.x);                              \
            acc.y = fdot2(SV(w, 2, 3), x2, acc.y);                              \
            acc.z = fdot2(SV(w, 4, 5), x2, acc.z);                              \
            acc.w = fdot2(SV(w, 6, 7), x2, acc.w);                              \
        }
        #pragma unroll
        for (int q = 0; q < 8; ++q) {
            h8 xa = haH[g * 8 + q];
            FC2_STEP(q, 0)
            FC2_STEP(q, 1)
            FC2_STEP(q, 2)
            FC2_STEP(q, 3)
        }
#undef FC2_STEP
        ((float4*)U.p2.red[g])[c] = acc;
    }
    __syncthreads();
    {
        float v = U.p2.red[0][tid] + U.p2.red[1][tid] + U.p2.red[2][tid] + U.p2.red[3][tid]
                  + fc2_b[tid];
        U.p2.hbh[tid] = (_Float16)fmaxf(v, 0.f);
    }
    __syncthreads();

    // ---- FC3 (256 -> 2) + tanh ----
    if (tid < 128) {
        int o = tid >> 6, l = tid & 63;
        float s = 0.f;
        #pragma unroll
        for (int m = 0; m < 4; m++) {
            int k = l + 64 * m;
            s = fmaf((float)U.p2.hbh[k], fc3_w[k * 2 + o], s);
        }
        #pragma unroll
        for (int off = 32; off >= 1; off >>= 1) s += __shfl_down(s, off, 64);
        if (l == 0) out[bix * 2 + o] = tanhf(s + fc3_b[o]);
    }
}

extern "C" void kernel_launch(void* const* d_in, const int* in_sizes, int n_in,
                              void* d_out, int out_size, void* d_ws, size_t ws_size,
                              hipStream_t stream) {
    const float* state24 = (const float*)d_in[0];
    const float* Wl1 = (const float*)d_in[1];
    const float* Wr1 = (const float*)d_in[2];
    const float* att1 = (const float*)d_in[3];
    const float* b1 = (const float*)d_in[4];
    const float* Wl2 = (const float*)d_in[5];
    const float* Wr2 = (const float*)d_in[6];
    const float* att2 = (const float*)d_in[7];
    const float* b2 = (const float*)d_in[8];
    const float* fc1_w = (const float*)d_in[9];
    const float* fc1_b = (const float*)d_in[10];
    const float* fc2_w = (const float*)d_in[11];
    const float* fc2_b = (const float*)d_in[12];
    const float* fc3_w = (const float*)d_in[13];
    const float* fc3_b = (const float*)d_in[14];
    float* out = (float*)d_out;

    h8* ws = (h8*)d_ws;                 // 14336 h8 = 224 KiB
    const h8* wsL = ws;
    const h8* wsR = ws + 2048;
    const h8* wsF1 = ws + 4096;
    const h8* wsF2 = ws + 6144;

    pack_weights_kernel<<<56, 256, 0, stream>>>(Wl2, Wr2, fc1_w, fc2_w, ws);

    int B = in_sizes[0] / 24;
    actor_fused_kernel<<<B, 256, 0, stream>>>(
        state24, Wl1, Wr1, att1, b1, att2, b2,
        fc1_b, fc2_b, fc3_w, fc3_b,
        wsL, wsR, wsF1, wsF2, out, B);
}

// Round 14
// 112.400 us; speedup vs baseline: 1.1305x; 1.0111x over previous
//
#include <hip/hip_runtime.h>
#include <hip/hip_fp16.h>
#include <math.h>

#define PI_D 3.141592653589793

typedef _Float16 h2 __attribute__((ext_vector_type(2)));
typedef _Float16 h4 __attribute__((ext_vector_type(4)));
typedef _Float16 h8 __attribute__((ext_vector_type(8)));
typedef unsigned short us8 __attribute__((ext_vector_type(8)));
typedef __fp16 f16v2 __attribute__((ext_vector_type(2)));
typedef __fp16 f16v8 __attribute__((ext_vector_type(8)));
typedef float f32x4 __attribute__((ext_vector_type(4)));

#define STR1 264     // gl1h/gr1h row stride in halves (528 B; 33 h8)
#define STR2H 72     // gl2h/gr2h fp16 row stride in halves (144 B)

#define SV(v, a, b) __builtin_shufflevector(v, v, a, b)

static __device__ __forceinline__ h2 pack_h2(float a, float b) {
    return __builtin_bit_cast(h2, __builtin_amdgcn_cvt_pkrtz(a, b));
}

static __device__ __forceinline__ float fdot2(h2 a, h2 b, float c) {
    return __builtin_amdgcn_fdot2(__builtin_bit_cast(f16v2, a),
                                  __builtin_bit_cast(f16v2, b), c, false);
}

static __device__ __forceinline__ h8 habs8(h8 x) {
    us8 u = __builtin_bit_cast(us8, x);
    us8 m = {0x7fff, 0x7fff, 0x7fff, 0x7fff, 0x7fff, 0x7fff, 0x7fff, 0x7fff};
    return __builtin_bit_cast(h8, (us8)(u & m));
}

static __device__ __forceinline__ f32x4 mfma16(h8 a, h8 b, f32x4 c) {
    return __builtin_amdgcn_mfma_f32_16x16x32_f16(
        __builtin_bit_cast(f16v8, a), __builtin_bit_cast(f16v8, b), c, 0, 0, 0);
}

static __device__ __forceinline__ void wave_fence() {
    asm volatile("" ::: "memory");
#if __has_builtin(__builtin_amdgcn_wave_barrier)
    __builtin_amdgcn_wave_barrier();
#endif
    asm volatile("" ::: "memory");
}

// ---- pre-pass: pack weights to fp16 (round-10 layouts) ----
__global__ __launch_bounds__(256) void pack_weights_kernel(
    const float* __restrict__ Wl2, const float* __restrict__ Wr2,
    const float* __restrict__ fc1_w, const float* __restrict__ fc2_w,
    h8* __restrict__ ws)
{
    int idx = blockIdx.x * 256 + threadIdx.x;
    if (idx < 4096) {
        const float* W = idx < 2048 ? Wl2 : Wr2;
        int t = idx & 2047;
        int ntile = t >> 9, rem = t & 511;
        int kchunk = rem >> 6, lane = rem & 63;
        int n = ntile * 16 + (lane & 15);
        int k0 = kchunk * 32 + (lane >> 4) * 8;
        h8 o;
        #pragma unroll
        for (int j = 0; j < 8; ++j) o[j] = (_Float16)W[(k0 + j) * 64 + n];
        ws[idx] = o;
    } else if (idx < 6144) {
        int t = idx - 4096;
        int k2 = t >> 6, c = t & 63;
        h8 o;
        #pragma unroll
        for (int q = 0; q < 4; ++q) {
            o[2 * q]     = (_Float16)fc1_w[(2 * k2) * 256 + 4 * c + q];
            o[2 * q + 1] = (_Float16)fc1_w[(2 * k2 + 1) * 256 + 4 * c + q];
        }
        ws[idx] = o;
    } else {
        int t = idx - 6144;
        int k2 = t >> 6, c = t & 63;
        h8 o;
        #pragma unroll
        for (int q = 0; q < 4; ++q) {
            o[2 * q]     = (_Float16)fc2_w[(2 * k2) * 256 + 4 * c + q];
            o[2 * q + 1] = (_Float16)fc2_w[(2 * k2 + 1) * 256 + 4 * c + q];
        }
        ws[idx] = o;
    }
}

__global__ __launch_bounds__(256, 2) void actor_fused_kernel(
    const float* __restrict__ state24,
    const float* __restrict__ Wl1, const float* __restrict__ Wr1,
    const float* __restrict__ att1, const float* __restrict__ b1,
    const float* __restrict__ att2, const float* __restrict__ b2,
    const float* __restrict__ fc1_b, const float* __restrict__ fc2_b,
    const float* __restrict__ fc3_w, const float* __restrict__ fc3_b,
    const h8* __restrict__ wsL, const h8* __restrict__ wsR,
    const h8* __restrict__ wsF1, const h8* __restrict__ wsF2,
    float* __restrict__ out, int B)
{
    const int bix = blockIdx.x;
    const int tid = threadIdx.x;
    const int smp0 = 2 * bix;
    if (smp0 >= B) return;
    const int smp1 = (smp0 + 1 < B) ? smp0 + 1 : smp0;

    __shared__ float sinL[20], cosL[20], laserL[2][20], robotL[2][4];
    __shared__ __align__(16) h2 attLh[128];
    __shared__ __align__(16) h2 att2Lh[32];
    __shared__ __align__(16) _Float16 gr1h[2][22 * STR1];
    __shared__ __align__(16) union {
        struct { _Float16 gl1h[2][22 * STR1];
                 float ePf[2][128 * 24];
                 float uv[2][168]; } p1;
        struct { _Float16 gl2h[2][21 * STR2H];
                 _Float16 gr2h[2][21 * STR2H];
                 _Float16 gl2hT[2][64 * 32];
                 float e2[2][32 * 24];
                 float u2v2[2][42];
                 float red[2][4][256];
                 _Float16 nfvh[2][64]; _Float16 hah[2][256]; _Float16 hbh[2][256]; } p2;
    } U;

    // ---- setup ----
    if (tid < 20) {
        double step = (PI_D + 0.03) / 20.0;
        float bound = (float)(-PI_D / 2.0 - 0.03 + (double)tid * step);
        float ang = bound + (float)(PI_D / 20.0);
        sinL[tid] = sinf(ang);
        cosL[tid] = cosf(ang);
        laserL[0][tid] = state24[smp0 * 24 + tid] * 0.1f;
        laserL[1][tid] = state24[smp1 * 24 + tid] * 0.1f;
    }
    if (tid >= 32 && tid < 40) {
        int s = (tid - 32) >> 2, q = (tid - 32) & 3;
        robotL[s][q] = state24[(s ? smp1 : smp0) * 24 + 20 + q];
    }
    if (tid < 128) {
        float2 ap = ((const float2*)att1)[tid];
        attLh[tid] = pack_h2(0.4f * ap.x, 0.4f * ap.y);
    }
    if (tid >= 128 && tid < 160) {
        float2 ap = ((const float2*)att2)[tid - 128];
        att2Lh[tid - 128] = pack_h2(0.4f * ap.x, 0.4f * ap.y);
    }
    __syncthreads();

    // ================= L1 block: wave h owns head h, both samples =================
    {
        const int h = tid >> 6;
        const int lane = tid & 63;

        // ---- transform1: weights loaded once, used for both samples ----
        {
            const int cp = lane & 31;
            const int half = lane >> 5;
            const int d2 = h * 32 + cp;
            float2 wl[7], wr[7];
            #pragma unroll
            for (int k = 0; k < 7; k++) {
                wl[k] = ((const float2*)Wl1)[k * 128 + d2];
                wr[k] = ((const float2*)Wr1)[k * 128 + d2];
            }
            if (half == 0) {
                h2 zz2 = {};
                #pragma unroll
                for (int s = 0; s < 2; ++s) {
                    ((h2*)(U.p1.gl1h[s] + 21 * STR1))[d2] = zz2;
                    ((h2*)(gr1h[s] + 21 * STR1))[d2] = zz2;
                }
            }
            const int base = half * 11;
            #pragma unroll
            for (int nn = 0; nn < 11; ++nn) {
                int node = base + nn;
                if (node < 21) {
                    #pragma unroll
                    for (int s = 0; s < 2; ++s) {
                        float a0, a1, b0, b1v;
                        if (node < 20) {
                            float l = laserL[s][node], sv = sinL[node], c = cosL[node];
                            a0 = l * wl[0].x + sv * wl[1].x + c * wl[2].x;
                            a1 = l * wl[0].y + sv * wl[1].y + c * wl[2].y;
                            b0 = l * wr[0].x + sv * wr[1].x + c * wr[2].x;
                            b1v = l * wr[0].y + sv * wr[1].y + c * wr[2].y;
                        } else {
                            float r0 = robotL[s][0], r1 = robotL[s][1], r2 = robotL[s][2], r3 = robotL[s][3];
                            a0 = r0 * wl[3].x + r1 * wl[4].x + r2 * wl[5].x + r3 * wl[6].x;
                            a1 = r0 * wl[3].y + r1 * wl[4].y + r2 * wl[5].y + r3 * wl[6].y;
                            b0 = r0 * wr[3].x + r1 * wr[4].x + r2 * wr[5].x + r3 * wr[6].x;
                            b1v = r0 * wr[3].y + r1 * wr[4].y + r2 * wr[5].y + r3 * wr[6].y;
                        }
                        ((h2*)(U.p1.gl1h[s] + node * STR1))[d2] = pack_h2(a0, a1);
                        ((h2*)(gr1h[s] + node * STR1))[d2] = pack_h2(b0, b1v);
                    }
                }
            }
        }
        wave_fence();

        // ---- logits1 (abs part) + u/v, both samples ----
        {
            h2 ar[32];
            #pragma unroll
            for (int q = 0; q < 32; ++q) ar[q] = attLh[h * 32 + q];

            #pragma unroll
            for (int s = 0; s < 2; ++s) {
                for (int it = 0; it < 7; ++it) {
                    int q = it * 64 + lane;
                    if (q < 441) {
                        int i = q / 21;
                        int j = q - i * 21;
                        const h8* gA8 = (const h8*)(U.p1.gl1h[s] + j * STR1 + h * 64);
                        const h8* gB8 = (const h8*)(gr1h[s] + i * STR1 + h * 64);
                        float m0 = 0.f, m1 = 0.f;
                        #pragma unroll
                        for (int ch = 0; ch < 8; ++ch) {
                            h8 x = gA8[ch] + gB8[ch];
                            h8 ax = habs8(x);
                            m0 = fdot2(SV(ax, 0, 1), ar[ch * 4 + 0], m0);
                            m1 = fdot2(SV(ax, 2, 3), ar[ch * 4 + 1], m1);
                            m0 = fdot2(SV(ax, 4, 5), ar[ch * 4 + 2], m0);
                            m1 = fdot2(SV(ax, 6, 7), ar[ch * 4 + 3], m1);
                        }
                        U.p1.ePf[s][(h * 32 + i) * 24 + j] = m0 + m1;
                    }
                }
            }
            if (lane < 42) {
                int isV = lane >= 21;
                int idx = isV ? lane - 21 : lane;
                #pragma unroll
                for (int s = 0; s < 2; ++s) {
                    const _Float16* rowp = (isV ? (const _Float16*)gr1h[s]
                                                : (const _Float16*)U.p1.gl1h[s]) + idx * STR1 + h * 64;
                    const h8* row8 = (const h8*)rowp;
                    float l0 = 0.f, l1 = 0.f;
                    #pragma unroll
                    for (int ch = 0; ch < 8; ++ch) {
                        h8 g = row8[ch];
                        l0 = fdot2(SV(g, 0, 1), ar[ch * 4 + 0], l0);
                        l1 = fdot2(SV(g, 2, 3), ar[ch * 4 + 1], l1);
                        l0 = fdot2(SV(g, 4, 5), ar[ch * 4 + 2], l0);
                        l1 = fdot2(SV(g, 6, 7), ar[ch * 4 + 3], l1);
                    }
                    U.p1.uv[s][(isV ? 84 : 0) + h * 21 + idx] = l0 + l1;
                }
            }
        }
        wave_fence();

        // ---- softmax1: lanes 0..20 s=0, 21..41 s=1; zero rows 21..31 both samples ----
        if (lane < 42) {
            int s = lane >= 21;
            int i = lane - s * 21;
            int r = h * 32 + i;
            float* row = U.p1.ePf[s] + r * 24;
            const float* uu = U.p1.uv[s] + h * 21;
            float vi = 1.5f * U.p1.uv[s][84 + h * 21 + i];
            float ebuf[21];
            float m = -1e30f;
            #pragma unroll
            for (int j = 0; j < 21; j++) {
                float e = row[j] + 1.5f * uu[j] + vi;
                ebuf[j] = e;
                m = fmaxf(m, e);
            }
            float sum = 0.f;
            #pragma unroll
            for (int j = 0; j < 21; j++) { float v = __expf(ebuf[j] - m); ebuf[j] = v; sum += v; }
            float rinv = 1.f / sum;
            h8* hp8 = (h8*)(U.p1.ePf[s]) + r * 6;
            h8 o0, o1, o2;
            #pragma unroll
            for (int q = 0; q < 8; ++q) o0[q] = (_Float16)(ebuf[q] * rinv);
            #pragma unroll
            for (int q = 0; q < 8; ++q) o1[q] = (_Float16)(ebuf[8 + q] * rinv);
            #pragma unroll
            for (int q = 0; q < 5; ++q) o2[q] = (_Float16)(ebuf[16 + q] * rinv);
            o2[5] = (_Float16)0.f; o2[6] = (_Float16)0.f; o2[7] = (_Float16)0.f;
            h8 zz = {};
            hp8[0] = o0; hp8[1] = o1; hp8[2] = o2;
            hp8[3] = zz; hp8[4] = zz; hp8[5] = zz;
        }
        {   // zero fp16 A-frag rows (h, 21..31) x 2 samples: 132 h8 slots
            h8 zz = {};
            for (int z = lane; z < 132; z += 64) {
                int s = z >= 66;
                int zz2 = z - s * 66;
                int rr = zz2 / 6, slot = zz2 - rr * 6;
                ((h8*)U.p1.ePf[s])[(h * 32 + 21 + rr) * 6 + slot] = zz;
            }
        }
        wave_fence();

        // ---- agg1 via MFMA, both samples; bias loaded once ----
        {
            const int mcol = lane & 15;
            const int quad = lane >> 4;
            h8 A0s[2], A1s[2];
            #pragma unroll
            for (int s = 0; s < 2; ++s) {
                const h8* Af = (const h8*)U.p1.ePf[s];
                A0s[s] = Af[(h * 32 + mcol) * 6 + quad];
                A1s[s] = Af[(h * 32 + 16 + mcol) * 6 + quad];
            }
            int rowoff[8];
            #pragma unroll
            for (int jj = 0; jj < 8; ++jj) {
                int rr = quad * 8 + jj;
                rowoff[jj] = (rr > 21 ? 21 : rr) * STR1;
            }
            const int colbase = h * 64 + mcol;
            f32x4 z4 = {0.f, 0.f, 0.f, 0.f};
            #pragma unroll
            for (int t = 0; t < 4; ++t) {
                int col = colbase + t * 16;
                float bb = b1[col];
                #pragma unroll
                for (int s = 0; s < 2; ++s) {
                    h8 bv;
                    #pragma unroll
                    for (int jj = 0; jj < 8; ++jj) bv[jj] = U.p1.gl1h[s][rowoff[jj] + col];
                    f32x4 d0 = mfma16(A0s[s], bv, z4);
                    f32x4 d1 = mfma16(A1s[s], bv, z4);
                    #pragma unroll
                    for (int r = 0; r < 4; ++r) {
                        int n0 = quad * 4 + r;
                        float v = d0[r] + bb;
                        v = v > 0.f ? v : __expf(v) - 1.f;
                        gr1h[s][n0 * STR1 + col] = (_Float16)v;
                        int n1 = 16 + quad * 4 + r;
                        if (n1 < 21) {
                            float w2 = d1[r] + bb;
                            w2 = w2 > 0.f ? w2 : __expf(w2) - 1.f;
                            gr1h[s][n1 * STR1 + col] = (_Float16)w2;
                        }
                    }
                }
            }
        }
    }
    __syncthreads();
    // ================= end L1 block =================

    // ---- layer-2 transforms via MFMA; B-frags loaded once per kc, used by both samples ----
    {
        const int lane = tid & 63;
        const int w = tid >> 6;
        const int mrow = lane & 15;
        const int quad = lane >> 4;
        int rowA1 = 16 + mrow; if (rowA1 > 21) rowA1 = 21;
        const h8* bL = wsL + w * 512 + lane;
        const h8* bR = wsR + w * 512 + lane;
        f32x4 aL0[2], aL1[2], aR0[2], aR1[2];
        #pragma unroll
        for (int s = 0; s < 2; ++s) {
            aL0[s] = (f32x4){0.f, 0.f, 0.f, 0.f}; aL1[s] = (f32x4){0.f, 0.f, 0.f, 0.f};
            aR0[s] = (f32x4){0.f, 0.f, 0.f, 0.f}; aR1[s] = (f32x4){0.f, 0.f, 0.f, 0.f};
        }
        #pragma unroll
        for (int kc = 0; kc < 8; ++kc) {
            h8 BL = bL[kc * 64];
            h8 BR = bR[kc * 64];
            #pragma unroll
            for (int s = 0; s < 2; ++s) {
                h8 A0 = *(const h8*)(gr1h[s] + mrow * STR1 + quad * 8 + kc * 32);
                h8 A1 = *(const h8*)(gr1h[s] + rowA1 * STR1 + quad * 8 + kc * 32);
                aL0[s] = mfma16(A0, BL, aL0[s]);
                aL1[s] = mfma16(A1, BL, aL1[s]);
                aR0[s] = mfma16(A0, BR, aR0[s]);
                aR1[s] = mfma16(A1, BR, aR1[s]);
            }
        }
        const int col = w * 16 + mrow;
        #pragma unroll
        for (int s = 0; s < 2; ++s) {
            #pragma unroll
            for (int r = 0; r < 4; ++r) {
                int row0 = quad * 4 + r;
                U.p2.gl2h[s][row0 * STR2H + col] = (_Float16)aL0[s][r];
                U.p2.gr2h[s][row0 * STR2H + col] = (_Float16)aR0[s][r];
                int row1 = 16 + row0;
                if (row1 < 21) {
                    U.p2.gl2h[s][row1 * STR2H + col] = (_Float16)aL1[s][r];
                    U.p2.gr2h[s][row1 * STR2H + col] = (_Float16)aR1[s][r];
                }
            }
            h2 lo0 = pack_h2(aL0[s][0], aL0[s][1]);
            h2 hi0 = pack_h2(aL0[s][2], aL0[s][3]);
            h4 p0 = __builtin_shufflevector(lo0, hi0, 0, 1, 2, 3);
            *(h4*)(U.p2.gl2hT[s] + col * 32 + quad * 4) = p0;
            h2 lo1 = pack_h2(aL1[s][0], aL1[s][1]);
            h2 hi1 = pack_h2(aL1[s][2], aL1[s][3]);
            h4 p1 = __builtin_shufflevector(lo1, hi1, 0, 1, 2, 3);
            *(h4*)(U.p2.gl2hT[s] + col * 32 + 16 + quad * 4) = p1;
        }
    }
    __syncthreads();

    // ---- layer-2 logits (abs part) both samples + u2/v2 in spare slots ----
    {
        h2 ar2[32];
        #pragma unroll
        for (int q = 0; q < 32; ++q) ar2[q] = att2Lh[q];

        #pragma unroll
        for (int it = 0; it < 4; ++it) {
            int t = it * 256 + tid;
            if (t < 882) {
                int s = t >= 441;
                int p = t - s * 441;
                int i = p / 21;
                int j = p - i * 21;
                const h8* gA8 = (const h8*)(U.p2.gl2h[s] + j * STR2H);
                const h8* gB8 = (const h8*)(U.p2.gr2h[s] + i * STR2H);
                float m0 = 0.f, m1 = 0.f;
                #pragma unroll
                for (int ch = 0; ch < 8; ++ch) {
                    h8 x = gA8[ch] + gB8[ch];
                    h8 ax = habs8(x);
                    m0 = fdot2(SV(ax, 0, 1), ar2[ch * 4 + 0], m0);
                    m1 = fdot2(SV(ax, 2, 3), ar2[ch * 4 + 1], m1);
                    m0 = fdot2(SV(ax, 4, 5), ar2[ch * 4 + 2], m0);
                    m1 = fdot2(SV(ax, 6, 7), ar2[ch * 4 + 3], m1);
                }
                U.p2.e2[s][i * 24 + j] = m0 + m1;
            } else if (t < 966) {
                int u = t - 882;                  // 0..83
                int s = u >= 42;
                int r = u - s * 42;
                int isV = r >= 21;
                int idx = r - isV * 21;
                const _Float16* rowp = (isV ? U.p2.gr2h[s] : U.p2.gl2h[s]) + idx * STR2H;
                const h8* row8 = (const h8*)rowp;
                float l0 = 0.f, l1 = 0.f;
                #pragma unroll
                for (int ch = 0; ch < 8; ++ch) {
                    h8 g = row8[ch];
                    l0 = fdot2(SV(g, 0, 1), ar2[ch * 4 + 0], l0);
                    l1 = fdot2(SV(g, 2, 3), ar2[ch * 4 + 1], l1);
                    l0 = fdot2(SV(g, 4, 5), ar2[ch * 4 + 2], l0);
                    l1 = fdot2(SV(g, 6, 7), ar2[ch * 4 + 3], l1);
                }
                U.p2.u2v2[s][isV * 21 + idx] = l0 + l1;
            }
        }
    }
    __syncthreads();

    // ---- softmax-2 both samples -> fp16 A-frag; zero rows 21..31 both ----
    if (tid < 42) {
        int s = tid >= 21;
        int i = tid - s * 21;
        float* row = U.p2.e2[s] + i * 24;
        const float* uu = U.p2.u2v2[s];
        float vi = 1.5f * U.p2.u2v2[s][21 + i];
        float ebuf[21];
        float m = -1e30f;
        #pragma unroll
        for (int j = 0; j < 21; j++) {
            float e = row[j] + 1.5f * uu[j] + vi;
            ebuf[j] = e;
            m = fmaxf(m, e);
        }
        float sum = 0.f;
        #pragma unroll
        for (int j = 0; j < 21; j++) { float v = __expf(ebuf[j] - m); ebuf[j] = v; sum += v; }
        float rinv = 1.f / sum;
        h8* hp8 = (h8*)(U.p2.e2[s]) + i * 6;
        h8 o0, o1, o2;
        #pragma unroll
        for (int q = 0; q < 8; ++q) o0[q] = (_Float16)(ebuf[q] * rinv);
        #pragma unroll
        for (int q = 0; q < 8; ++q) o1[q] = (_Float16)(ebuf[8 + q] * rinv);
        #pragma unroll
        for (int q = 0; q < 5; ++q) o2[q] = (_Float16)(ebuf[16 + q] * rinv);
        o2[5] = (_Float16)0.f; o2[6] = (_Float16)0.f; o2[7] = (_Float16)0.f;
        h8 zz = {};
        hp8[0] = o0; hp8[1] = o1; hp8[2] = o2;
        hp8[3] = zz; hp8[4] = zz; hp8[5] = zz;
    } else if (tid < 174) {
        int z = tid - 42;                 // 0..131: rows 21..31 x 6 slots x 2 samples
        int s = z >= 66;
        int zz2 = z - s * 66;
        int rr = zz2 / 6, slot = zz2 - rr * 6;
        h8 zz = {};
        ((h8*)U.p2.e2[s])[(21 + rr) * 6 + slot] = zz;
    }
    __syncthreads();

    // ---- agg2 + mean-pool via MFMA -> nfvh, both samples ----
    {
        const int lane = tid & 63;
        const int w = tid >> 6;
        const int mcol = lane & 15;
        const int quad = lane >> 4;
        const int col = w * 16 + mcol;
        float bb = b2[col];
        f32x4 z4 = {0.f, 0.f, 0.f, 0.f};
        #pragma unroll
        for (int s = 0; s < 2; ++s) {
            const h8* Af2 = (const h8*)U.p2.e2[s];
            h8 A0 = Af2[mcol * 6 + quad];
            h8 A1 = Af2[(16 + mcol) * 6 + quad];
            h8 bv = *(const h8*)(U.p2.gl2hT[s] + col * 32 + quad * 8);
            f32x4 d0 = mfma16(A0, bv, z4);
            f32x4 d1 = mfma16(A1, bv, z4);
            float sum = (d0[0] + d0[1]) + (d0[2] + d0[3])
                      + (d1[0] + d1[1]) + (d1[2] + d1[3]);
            sum += __shfl_xor(sum, 16, 64);
            sum += __shfl_xor(sum, 32, 64);
            if (quad == 0) U.p2.nfvh[s][col] = (_Float16)(sum * (1.f / 21.f) + bb);
        }
    }
    __syncthreads();

    // ---- FC1 (64 -> 256): weights loaded once, both samples ----
    {
        int c = tid & 63, g = tid >> 6;
        float4 acc0 = {0.f, 0.f, 0.f, 0.f}, acc1 = {0.f, 0.f, 0.f, 0.f};
        #pragma unroll
        for (int kk = 0; kk < 8; ++kk) {
            int k2 = g * 8 + kk;
            h8 w = wsF1[k2 * 64 + c];
            h2 x0 = ((const h2*)U.p2.nfvh[0])[k2];
            h2 x1 = ((const h2*)U.p2.nfvh[1])[k2];
            acc0.x = fdot2(SV(w, 0, 1), x0, acc0.x);
            acc0.y = fdot2(SV(w, 2, 3), x0, acc0.y);
            acc0.z = fdot2(SV(w, 4, 5), x0, acc0.z);
            acc0.w = fdot2(SV(w, 6, 7), x0, acc0.w);
            acc1.x = fdot2(SV(w, 0, 1), x1, acc1.x);
            acc1.y = fdot2(SV(w, 2, 3), x1, acc1.y);
            acc1.z = fdot2(SV(w, 4, 5), x1, acc1.z);
            acc1.w = fdot2(SV(w, 6, 7), x1, acc1.w);
        }
        ((float4*)U.p2.red[0][g])[c] = acc0;
        ((float4*)U.p2.red[1][g])[c] = acc1;
    }
    __syncthreads();
    {
        float bb = fc1_b[tid];
        #pragma unroll
        for (int s = 0; s < 2; ++s) {
            float v = U.p2.red[s][0][tid] + U.p2.red[s][1][tid]
                    + U.p2.red[s][2][tid] + U.p2.red[s][3][tid] + bb;
            U.p2.hah[s][tid] = (_Float16)fmaxf(v, 0.f);
        }
    }
    __syncthreads();

    // ---- FC2 (256 -> 256): weights loaded once, both samples ----
    {
        int c = tid & 63, g = tid >> 6;
        const h8* ha0 = (const h8*)U.p2.hah[0];
        const h8* ha1 = (const h8*)U.p2.hah[1];
        float4 acc0 = {0.f, 0.f, 0.f, 0.f}, acc1 = {0.f, 0.f, 0.f, 0.f};
#define FC2_STEP(q, p)                                                          \
        {                                                                       \
            int k2 = g * 32 + (q) * 4 + (p);                                    \
            h8 w = wsF2[k2 * 64 + c];                                           \
            h2 x0 = __builtin_shufflevector(xa0, xa0, 2 * (p), 2 * (p) + 1);    \
            h2 x1 = __builtin_shufflevector(xa1, xa1, 2 * (p), 2 * (p) + 1);    \
            acc0.x = fdot2(SV(w, 0, 1), x0, acc0.x);                            \
            acc0.y = fdot2(SV(w, 2, 3), x0, acc0.y);                            \
            acc0.z = fdot2(SV(w, 4, 5), x0, acc0.z);                            \
            acc0.w = fdot2(SV(w, 6, 7), x0, acc0.w);                            \
            acc1.x = fdot2(SV(w, 0, 1), x1, acc1.x);                            \
            acc1.y = fdot2(SV(w, 2, 3), x1, acc1.y);                            \
            acc1.z = fdot2(SV(w, 4, 5), x1, acc1.z);                            \
            acc1.w = fdot2(SV(w, 6, 7), x1, acc1.w);                            \
        }
        #pragma unroll
        for (int q = 0; q < 8; ++q) {
            h8 xa0 = ha0[g * 8 + q];
            h8 xa1 = ha1[g * 8 + q];
            FC2_STEP(q, 0)
            FC2_STEP(q, 1)
            FC2_STEP(q, 2)
            FC2_STEP(q, 3)
        }
#undef FC2_STEP
        ((float4*)U.p2.red[0][g])[c] = acc0;
        ((float4*)U.p2.red[1][g])[c] = acc1;
    }
    __syncthreads();
    {
        float bb = fc2_b[tid];
        #pragma unroll
        for (int s = 0; s < 2; ++s) {
            float v = U.p2.red[s][0][tid] + U.p2.red[s][1][tid]
                    + U.p2.red[s][2][tid] + U.p2.red[s][3][tid] + bb;
            U.p2.hbh[s][tid] = (_Float16)fmaxf(v, 0.f);
        }
    }
    __syncthreads();

    // ---- FC3 (256 -> 2) + tanh: 4 wave-groups = (o, s) pairs ----
    {
        int g = tid >> 6;                 // 0..3
        int o = g & 1, s = g >> 1;
        int l = tid & 63;
        float sum = 0.f;
        #pragma unroll
        for (int m = 0; m < 4; m++) {
            int k = l + 64 * m;
            sum = fmaf((float)U.p2.hbh[s][k], fc3_w[k * 2 + o], sum);
        }
        #pragma unroll
        for (int off = 32; off >= 1; off >>= 1) sum += __shfl_down(sum, off, 64);
        if (l == 0 && smp0 + s < B) out[(smp0 + s) * 2 + o] = tanhf(sum + fc3_b[o]);
    }
}

extern "C" void kernel_launch(void* const* d_in, const int* in_sizes, int n_in,
                              void* d_out, int out_size, void* d_ws, size_t ws_size,
                              hipStream_t stream) {
    const float* state24 = (const float*)d_in[0];
    const float* Wl1 = (const float*)d_in[1];
    const float* Wr1 = (const float*)d_in[2];
    const float* att1 = (const float*)d_in[3];
    const float* b1 = (const float*)d_in[4];
    const float* Wl2 = (const float*)d_in[5];
    const float* Wr2 = (const float*)d_in[6];
    const float* att2 = (const float*)d_in[7];
    const float* b2 = (const float*)d_in[8];
    const float* fc1_w = (const float*)d_in[9];
    const float* fc1_b = (const float*)d_in[10];
    const float* fc2_w = (const float*)d_in[11];
    const float* fc2_b = (const float*)d_in[12];
    const float* fc3_w = (const float*)d_in[13];
    const float* fc3_b = (const float*)d_in[14];
    float* out = (float*)d_out;

    h8* ws = (h8*)d_ws;                 // 14336 h8 = 224 KiB
    const h8* wsL = ws;
    const h8* wsR = ws + 2048;
    const h8* wsF1 = ws + 4096;
    const h8* wsF2 = ws + 6144;

    pack_weights_kernel<<<56, 256, 0, stream>>>(Wl2, Wr2, fc1_w, fc2_w, ws);

    int B = in_sizes[0] / 24;
    int nb = (B + 1) / 2;
    actor_fused_kernel<<<nb, 256, 0, stream>>>(
        state24, Wl1, Wr1, att1, b1, att2, b2,
        fc1_b, fc2_b, fc3_w, fc3_b,
        wsL, wsR, wsF1, wsF2, out, B);
}